// Round 1
// baseline (1524.743 us; speedup 1.0000x reference)
//
#include <hip/hip_runtime.h>
#include <math.h>

#define L 4096
#define CDIM 256
#define DIN 512
#define DSTATE 16
#define DTR 16
#define BATCH 4

__device__ __forceinline__ float silu_f(float x) { return x / (1.f + __expf(-x)); }
__device__ __forceinline__ float softplus_f(float x) {
    return (x > 20.f) ? x : log1pf(__expf(x));
}

// ---------------- generic tiled fp32 GEMM ----------------
// Out[b,m,n] = sum_k A * W[n*K+k]  (+epilogue)
// A_KMAJOR: A[b*strideAb + k*M + m] (k<kSplit -> A0 else A1 with k-kSplit)
// else:     A[b*strideAb + m*K + k]
enum { EPI_BIAS = 0, EPI_SPLITUZ = 1, EPI_DBC = 2, EPI_SOFTPLUS = 3 };

template<int EPI, bool A_KMAJOR>
__global__ __launch_bounds__(256)
void gemm_kernel(const float* __restrict__ A0, const float* __restrict__ A1,
                 const float* __restrict__ Wt, const float* __restrict__ bias,
                 float* __restrict__ O0, float* __restrict__ O1, float* __restrict__ O2,
                 int M, int N, int K, int kSplit, long strideAb)
{
    __shared__ float As[16][68];   // stride 68: float4-aligned, <=2-way conflicts
    __shared__ float Ws[16][68];
    const int b  = blockIdx.z;
    const int m0 = blockIdx.x * 64;
    const int n0 = blockIdx.y * 64;
    const int tid = threadIdx.x;
    const int tn = tid & 15, tm = tid >> 4;
    float acc[4][4] = {};
    for (int k0 = 0; k0 < K; k0 += 16) {
        if (A_KMAJOR) {
            int m = tid & 63, kk = tid >> 6;
            #pragma unroll
            for (int p = 0; p < 4; ++p) {
                int k = kk + p * 4;
                int kg = k0 + k;
                const float* Ap = (kg < kSplit) ? A0 : A1;
                int kl = (kg < kSplit) ? kg : (kg - kSplit);
                As[k][m] = Ap[(long)b * strideAb + (long)kl * M + (m0 + m)];
            }
        } else {
            int k = tid & 15, mm = tid >> 4;
            #pragma unroll
            for (int p = 0; p < 4; ++p) {
                int m = mm + p * 16;
                As[k][m] = A0[(long)b * strideAb + (long)(m0 + m) * K + (k0 + k)];
            }
        }
        {
            int k = tid & 15, nn = tid >> 4;
            #pragma unroll
            for (int p = 0; p < 4; ++p) {
                int n = nn + p * 16;
                float v = 0.f;
                if (n0 + n < N) v = Wt[(long)(n0 + n) * K + (k0 + k)];
                Ws[k][n] = v;
            }
        }
        __syncthreads();
        #pragma unroll
        for (int k = 0; k < 16; ++k) {
            float4 a = *(const float4*)&As[k][tm * 4];
            float4 w = *(const float4*)&Ws[k][tn * 4];
            float av[4] = {a.x, a.y, a.z, a.w};
            float wv[4] = {w.x, w.y, w.z, w.w};
            #pragma unroll
            for (int i = 0; i < 4; ++i)
                #pragma unroll
                for (int j = 0; j < 4; ++j)
                    acc[i][j] += av[i] * wv[j];
        }
        __syncthreads();
    }
    #pragma unroll
    for (int i = 0; i < 4; ++i) {
        int m = m0 + tm * 4 + i;
        long rowb = (long)b * M + m;
        #pragma unroll
        for (int j = 0; j < 4; ++j) {
            int n = n0 + tn * 4 + j;
            if (n >= N) continue;
            float v = acc[i][j];
            if (EPI == EPI_BIAS) {
                if (bias) v += bias[n];
                O0[rowb * N + n] = v;
            } else if (EPI == EPI_SPLITUZ) {
                if (n < DIN) O0[rowb * DIN + n] = v;
                else         O1[rowb * DIN + (n - DIN)] = v;
            } else if (EPI == EPI_DBC) {
                if (n < 16)      O0[rowb * 16 + n] = v;
                else if (n < 32) O1[rowb * 16 + (n - 16)] = v;
                else             O2[rowb * 16 + (n - 32)] = v;
            } else if (EPI == EPI_SOFTPLUS) {
                v += bias[n];
                O0[rowb * N + n] = softplus_f(v);
            }
        }
    }
}

// ---------------- depthwise causal conv (k=4) + silu ----------------
__global__ __launch_bounds__(256)
void conv_silu_kernel(const float* __restrict__ u_pre, const float* __restrict__ cw,
                      const float* __restrict__ cb, float* __restrict__ u)
{
    long idx = (long)blockIdx.x * blockDim.x + threadIdx.x;
    int d = (int)(idx % DIN);
    long bl = idx / DIN;
    int l = (int)(bl % L);
    long brow = bl - l;
    float v = cb[d];
    #pragma unroll
    for (int j = 0; j < 4; ++j) {
        int li = l - 3 + j;
        if (li >= 0) v += u_pre[(brow + li) * DIN + d] * cw[d * 4 + j];
    }
    u[idx] = silu_f(v);
}

// ---------------- selective scan (sequential over L), fused y2 ----------------
#define DG 8
#define TCH 64
__global__ __launch_bounds__(128)
void scan_kernel(const float* __restrict__ delta, const float* __restrict__ u,
                 const float* __restrict__ Bm, const float* __restrict__ Cm,
                 const float* __restrict__ z, const float* __restrict__ A_log,
                 const float* __restrict__ Dp, float* __restrict__ y2)
{
    __shared__ float sD[TCH][DG], sU[TCH][DG], sZ[TCH][DG], sY[TCH][DG];
    __shared__ float sB[TCH][DSTATE], sC[TCH][DSTATE];
    const int b = blockIdx.x / (DIN / DG);
    const int g = blockIdx.x % (DIN / DG);
    const int d0 = g * DG;
    const int tid = threadIdx.x;
    const int dd = tid >> 4, s = tid & 15;
    const float Aval = -__expf(A_log[(d0 + dd) * DSTATE + s]);
    float h = 0.f;
    for (int t0 = 0; t0 < L; t0 += TCH) {
        for (int i = tid; i < TCH * DG; i += 128) {
            int t = i / DG, j = i % DG;
            long gidx = ((long)b * L + t0 + t) * DIN + d0 + j;
            sD[t][j] = delta[gidx];
            sU[t][j] = u[gidx];
            sZ[t][j] = z[gidx];
        }
        for (int i = tid; i < TCH * DSTATE; i += 128) {
            int t = i / DSTATE, ss = i % DSTATE;
            long gidx = ((long)b * L + t0 + t) * DSTATE + ss;
            sB[t][ss] = Bm[gidx];
            sC[t][ss] = Cm[gidx];
        }
        __syncthreads();
        #pragma unroll 4
        for (int t = 0; t < TCH; ++t) {
            float dlt = sD[t][dd];
            float uu  = sU[t][dd];
            float dA  = __expf(dlt * Aval);
            h = h * dA + dlt * uu * sB[t][s];
            float p = h * sC[t][s];
            p += __shfl_xor(p, 1);
            p += __shfl_xor(p, 2);
            p += __shfl_xor(p, 4);
            p += __shfl_xor(p, 8);
            if (s == 0) sY[t][dd] = p;
        }
        __syncthreads();
        for (int i = tid; i < TCH * DG; i += 128) {
            int t = i / DG, j = i % DG;
            long gidx = ((long)b * L + t0 + t) * DIN + d0 + j;
            float yy = sY[t][j] + sU[t][j] * Dp[d0 + j];
            y2[gidx] = yy * silu_f(sZ[t][j]);
        }
        __syncthreads();
    }
}

// ---------------- LayerNorm over C + transpose to (B,C,L) ----------------
__global__ __launch_bounds__(256)
void ln_kernel(const float* __restrict__ X, const float* __restrict__ gamma,
               const float* __restrict__ beta, float* __restrict__ out)
{
    __shared__ float tile[32][257];
    __shared__ float sMu[32], sRs[32];
    const int l0 = blockIdx.x * 32;
    const int b  = blockIdx.y;
    const int tid = threadIdx.x;
    for (int i = tid; i < 32 * 256; i += 256) {
        int l = i >> 8, c = i & 255;
        tile[l][c] = X[((long)b * L + l0 + l) * CDIM + c];
    }
    __syncthreads();
    {
        int l = tid >> 3, sub = tid & 7;
        float s1 = 0.f, s2 = 0.f;
        for (int c = sub * 32; c < sub * 32 + 32; ++c) {
            float v = tile[l][c];
            s1 += v; s2 += v * v;
        }
        s1 += __shfl_xor(s1, 1); s2 += __shfl_xor(s2, 1);
        s1 += __shfl_xor(s1, 2); s2 += __shfl_xor(s2, 2);
        s1 += __shfl_xor(s1, 4); s2 += __shfl_xor(s2, 4);
        if (sub == 0) {
            float mu = s1 * (1.f / 256.f);
            float var = s2 * (1.f / 256.f) - mu * mu;
            sMu[l] = mu;
            sRs[l] = rsqrtf(var + 1e-5f);
        }
    }
    __syncthreads();
    for (int i = tid; i < 32 * 256; i += 256) {
        int ll = i & 31, c = i >> 5;
        float v = (tile[ll][c] - sMu[ll]) * sRs[ll] * gamma[c] + beta[c];
        out[((long)b * CDIM + c) * L + l0 + ll] = v;
    }
}

extern "C" void kernel_launch(void* const* d_in, const int* in_sizes, int n_in,
                              void* d_out, int out_size, void* d_ws, size_t ws_size,
                              hipStream_t stream)
{
    const float* sp   = (const float*)d_in[0];
    const float* fq   = (const float*)d_in[1];
    const float* Wp   = (const float*)d_in[2];
    const float* bp   = (const float*)d_in[3];
    const float* Win  = (const float*)d_in[4];
    const float* cw   = (const float*)d_in[5];
    const float* cb   = (const float*)d_in[6];
    const float* Wx   = (const float*)d_in[7];
    const float* Wdt  = (const float*)d_in[8];
    const float* bdt  = (const float*)d_in[9];
    const float* Alog = (const float*)d_in[10];
    const float* Dp   = (const float*)d_in[11];
    const float* Wout = (const float*)d_in[12];
    const float* gam  = (const float*)d_in[13];
    const float* bet  = (const float*)d_in[14];
    float* out = (float*)d_out;
    float* ws  = (float*)d_ws;

    size_t off = 0;
    float* x_proj = ws + off; off += (size_t)BATCH * L * CDIM;  // reused as x_mixed
    float* u_pre  = ws + off; off += (size_t)BATCH * L * DIN;   // reused as delta
    float* zb     = ws + off; off += (size_t)BATCH * L * DIN;
    float* ub     = ws + off; off += (size_t)BATCH * L * DIN;
    float* yb     = ws + off; off += (size_t)BATCH * L * DIN;
    float* dtb    = ws + off; off += (size_t)BATCH * L * DTR;
    float* Bmb    = ws + off; off += (size_t)BATCH * L * DSTATE;
    float* Cmb    = ws + off; off += (size_t)BATCH * L * DSTATE;

    dim3 blk(256);
    // GEMM1: x_proj = x_cat @ Wp^T + bp   (A K-major, split spatial/freq at k=256)
    gemm_kernel<EPI_BIAS, true><<<dim3(L / 64, CDIM / 64, BATCH), blk, 0, stream>>>(
        sp, fq, Wp, bp, x_proj, nullptr, nullptr, L, CDIM, 2 * CDIM, CDIM, (long)CDIM * L);
    // GEMM2: xz = x_proj @ Win^T -> split u_pre / z
    gemm_kernel<EPI_SPLITUZ, false><<<dim3(L / 64, 2 * DIN / 64, BATCH), blk, 0, stream>>>(
        x_proj, nullptr, Win, nullptr, u_pre, zb, nullptr, L, 2 * DIN, CDIM, 1 << 30, (long)L * CDIM);
    // depthwise causal conv + silu
    conv_silu_kernel<<<dim3((BATCH * L * DIN) / 256), blk, 0, stream>>>(u_pre, cw, cb, ub);
    // GEMM3: dbc = u @ Wx^T -> split dt / Bm / Cm
    gemm_kernel<EPI_DBC, false><<<dim3(L / 64, 1, BATCH), blk, 0, stream>>>(
        ub, nullptr, Wx, nullptr, dtb, Bmb, Cmb, L, 48, DIN, 1 << 30, (long)L * DIN);
    // GEMM4: delta = softplus(dt @ Wdt^T + bdt)  (writes into u_pre buffer)
    gemm_kernel<EPI_SOFTPLUS, false><<<dim3(L / 64, DIN / 64, BATCH), blk, 0, stream>>>(
        dtb, nullptr, Wdt, bdt, u_pre, nullptr, nullptr, L, DIN, DTR, 1 << 30, (long)L * DTR);
    // selective scan + fused y2 = (y + u*D) * silu(z)
    scan_kernel<<<dim3(BATCH * (DIN / DG)), dim3(128), 0, stream>>>(
        u_pre, ub, Bmb, Cmb, zb, Alog, Dp, yb);
    // GEMM5: x_mixed = y2 @ Wout^T  (into x_proj buffer)
    gemm_kernel<EPI_BIAS, false><<<dim3(L / 64, CDIM / 64, BATCH), blk, 0, stream>>>(
        yb, nullptr, Wout, nullptr, x_proj, nullptr, nullptr, L, CDIM, DIN, 1 << 30, (long)L * DIN);
    // LayerNorm + transpose to (B,C,H,W)
    ln_kernel<<<dim3(L / 32, BATCH), blk, 0, stream>>>(x_proj, gam, bet, out);
}

// Round 2
// 734.747 us; speedup vs baseline: 2.0752x; 2.0752x over previous
//
#include <hip/hip_runtime.h>
#include <math.h>

#define L 4096
#define CDIM 256
#define DIN 512
#define DSTATE 16
#define DTR 16
#define BATCH 4

__device__ __forceinline__ float silu_f(float x) { return x / (1.f + __expf(-x)); }
__device__ __forceinline__ float softplus_f(float x) {
    return (x > 20.f) ? x : log1pf(__expf(x));
}

// ---------------- generic tiled fp32 GEMM ----------------
enum { EPI_BIAS = 0, EPI_SPLITUZ = 1, EPI_DBC = 2, EPI_SOFTPLUS = 3 };

template<int EPI, bool A_KMAJOR>
__global__ __launch_bounds__(256)
void gemm_kernel(const float* __restrict__ A0, const float* __restrict__ A1,
                 const float* __restrict__ Wt, const float* __restrict__ bias,
                 float* __restrict__ O0, float* __restrict__ O1, float* __restrict__ O2,
                 int M, int N, int K, int kSplit, long strideAb)
{
    __shared__ float As[16][68];
    __shared__ float Ws[16][68];
    const int b  = blockIdx.z;
    const int m0 = blockIdx.x * 64;
    const int n0 = blockIdx.y * 64;
    const int tid = threadIdx.x;
    const int tn = tid & 15, tm = tid >> 4;
    float acc[4][4] = {};
    for (int k0 = 0; k0 < K; k0 += 16) {
        if (A_KMAJOR) {
            int m = tid & 63, kk = tid >> 6;
            #pragma unroll
            for (int p = 0; p < 4; ++p) {
                int k = kk + p * 4;
                int kg = k0 + k;
                const float* Ap = (kg < kSplit) ? A0 : A1;
                int kl = (kg < kSplit) ? kg : (kg - kSplit);
                As[k][m] = Ap[(long)b * strideAb + (long)kl * M + (m0 + m)];
            }
        } else {
            int k = tid & 15, mm = tid >> 4;
            #pragma unroll
            for (int p = 0; p < 4; ++p) {
                int m = mm + p * 16;
                As[k][m] = A0[(long)b * strideAb + (long)(m0 + m) * K + (k0 + k)];
            }
        }
        {
            int k = tid & 15, nn = tid >> 4;
            #pragma unroll
            for (int p = 0; p < 4; ++p) {
                int n = nn + p * 16;
                float v = 0.f;
                if (n0 + n < N) v = Wt[(long)(n0 + n) * K + (k0 + k)];
                Ws[k][n] = v;
            }
        }
        __syncthreads();
        #pragma unroll
        for (int k = 0; k < 16; ++k) {
            float4 a = *(const float4*)&As[k][tm * 4];
            float4 w = *(const float4*)&Ws[k][tn * 4];
            float av[4] = {a.x, a.y, a.z, a.w};
            float wv[4] = {w.x, w.y, w.z, w.w};
            #pragma unroll
            for (int i = 0; i < 4; ++i)
                #pragma unroll
                for (int j = 0; j < 4; ++j)
                    acc[i][j] += av[i] * wv[j];
        }
        __syncthreads();
    }
    #pragma unroll
    for (int i = 0; i < 4; ++i) {
        int m = m0 + tm * 4 + i;
        long rowb = (long)b * M + m;
        #pragma unroll
        for (int j = 0; j < 4; ++j) {
            int n = n0 + tn * 4 + j;
            if (n >= N) continue;
            float v = acc[i][j];
            if (EPI == EPI_BIAS) {
                if (bias) v += bias[n];
                O0[rowb * N + n] = v;
            } else if (EPI == EPI_SPLITUZ) {
                if (n < DIN) O0[rowb * DIN + n] = v;
                else         O1[rowb * DIN + (n - DIN)] = v;
            } else if (EPI == EPI_DBC) {
                if (n < 16)      O0[rowb * 16 + n] = v;
                else if (n < 32) O1[rowb * 16 + (n - 16)] = v;
                else             O2[rowb * 16 + (n - 32)] = v;
            } else if (EPI == EPI_SOFTPLUS) {
                v += bias[n];
                O0[rowb * N + n] = softplus_f(v);
            }
        }
    }
}

// ---------------- depthwise causal conv (k=4) + silu ----------------
__global__ __launch_bounds__(256)
void conv_silu_kernel(const float* __restrict__ u_pre, const float* __restrict__ cw,
                      const float* __restrict__ cb, float* __restrict__ u)
{
    long idx = (long)blockIdx.x * blockDim.x + threadIdx.x;
    int d = (int)(idx % DIN);
    long bl = idx / DIN;
    int l = (int)(bl % L);
    long brow = bl - l;
    float v = cb[d];
    #pragma unroll
    for (int j = 0; j < 4; ++j) {
        int li = l - 3 + j;
        if (li >= 0) v += u_pre[(brow + li) * DIN + d] * cw[d * 4 + j];
    }
    u[idx] = silu_f(v);
}

// ---------------- chunked parallel selective scan ----------------
// h[t] = a[t]*h[t-1] + x[t], a = exp(delta*A), x = delta*u*B
// 64 chunks of 64 steps; phase1: chunk transition (P, X); phase2: combine;
// phase3: replay with known h0, reduce y over s, fused y2 epilogue.
#define DG 8
#define NDG (DIN / DG)
#define NC 64
#define LC (L / NC)

__global__ __launch_bounds__(128)
void scan_phase1(const float* __restrict__ delta, const float* __restrict__ u,
                 const float* __restrict__ Bm, const float* __restrict__ A_log,
                 float* __restrict__ Asum, float* __restrict__ Xsum)
{
    __shared__ float sD[LC][DG], sU[LC][DG], sB[LC][DSTATE];
    const int c = blockIdx.x % NC;
    const int g = (blockIdx.x / NC) % NDG;
    const int b = blockIdx.x / (NC * NDG);
    const int d0 = g * DG;
    const int tid = threadIdx.x;
    const int dd = tid >> 4, s = tid & 15;
    const float Aval = -__expf(A_log[(d0 + dd) * DSTATE + s]);
    const int t0 = c * LC;
    for (int i = tid; i < LC * DG; i += 128) {
        int t = i / DG, j = i % DG;
        long gidx = ((long)b * L + t0 + t) * DIN + d0 + j;
        sD[t][j] = delta[gidx];
        sU[t][j] = u[gidx];
    }
    for (int i = tid; i < LC * DSTATE; i += 128) {
        int t = i >> 4, ss = i & 15;
        sB[t][ss] = Bm[((long)b * L + t0 + t) * DSTATE + ss];
    }
    __syncthreads();
    float P = 1.f, X = 0.f;
    #pragma unroll 8
    for (int t = 0; t < LC; ++t) {
        float dlt = sD[t][dd];
        float a = __expf(dlt * Aval);
        P *= a;
        X = a * X + dlt * sU[t][dd] * sB[t][s];
    }
    long oidx = (((long)b * NC + c) * DIN + d0 + dd) * DSTATE + s;
    Asum[oidx] = P;
    Xsum[oidx] = X;
}

__global__ __launch_bounds__(256)
void scan_phase2(const float* __restrict__ Asum, float* __restrict__ Xsum)
{
    int lane = blockIdx.x * 256 + threadIdx.x;       // (b*DIN + d)*16 + s
    int b = lane / (DIN * DSTATE);
    int rem = lane % (DIN * DSTATE);
    float h = 0.f;
    for (int c = 0; c < NC; ++c) {
        long idx = ((long)b * NC + c) * (DIN * DSTATE) + rem;
        float A = Asum[idx], X = Xsum[idx];
        Xsum[idx] = h;                               // h at START of chunk c
        h = A * h + X;
    }
}

__global__ __launch_bounds__(128)
void scan_phase3(const float* __restrict__ delta, const float* __restrict__ u,
                 const float* __restrict__ Bm, const float* __restrict__ Cm,
                 const float* __restrict__ z, const float* __restrict__ A_log,
                 const float* __restrict__ Dp, const float* __restrict__ Hinit,
                 float* __restrict__ y2)
{
    __shared__ float sD[LC][DG], sU[LC][DG], sZ[LC][DG], sY[LC][DG];
    __shared__ float sB[LC][DSTATE], sC[LC][DSTATE];
    const int c = blockIdx.x % NC;
    const int g = (blockIdx.x / NC) % NDG;
    const int b = blockIdx.x / (NC * NDG);
    const int d0 = g * DG;
    const int tid = threadIdx.x;
    const int dd = tid >> 4, s = tid & 15;
    const float Aval = -__expf(A_log[(d0 + dd) * DSTATE + s]);
    const int t0 = c * LC;
    for (int i = tid; i < LC * DG; i += 128) {
        int t = i / DG, j = i % DG;
        long gidx = ((long)b * L + t0 + t) * DIN + d0 + j;
        sD[t][j] = delta[gidx];
        sU[t][j] = u[gidx];
        sZ[t][j] = z[gidx];
    }
    for (int i = tid; i < LC * DSTATE; i += 128) {
        int t = i >> 4, ss = i & 15;
        long gidx = ((long)b * L + t0 + t) * DSTATE + ss;
        sB[t][ss] = Bm[gidx];
        sC[t][ss] = Cm[gidx];
    }
    float h = Hinit[(((long)b * NC + c) * DIN + d0 + dd) * DSTATE + s];
    __syncthreads();
    #pragma unroll 4
    for (int t = 0; t < LC; ++t) {
        float dlt = sD[t][dd];
        float a = __expf(dlt * Aval);
        h = h * a + dlt * sU[t][dd] * sB[t][s];
        float p = h * sC[t][s];
        p += __shfl_xor(p, 1);
        p += __shfl_xor(p, 2);
        p += __shfl_xor(p, 4);
        p += __shfl_xor(p, 8);
        if (s == 0) sY[t][dd] = p;
    }
    __syncthreads();
    for (int i = tid; i < LC * DG; i += 128) {
        int t = i / DG, j = i % DG;
        long gidx = ((long)b * L + t0 + t) * DIN + d0 + j;
        float yy = sY[t][j] + sU[t][j] * Dp[d0 + j];
        y2[gidx] = yy * silu_f(sZ[t][j]);
    }
}

// ---------------- LayerNorm over C + transpose to (B,C,L) ----------------
__global__ __launch_bounds__(256)
void ln_kernel(const float* __restrict__ X, const float* __restrict__ gamma,
               const float* __restrict__ beta, float* __restrict__ out)
{
    __shared__ float tile[32][257];
    __shared__ float sMu[32], sRs[32];
    const int l0 = blockIdx.x * 32;
    const int b  = blockIdx.y;
    const int tid = threadIdx.x;
    for (int i = tid; i < 32 * 256; i += 256) {
        int l = i >> 8, c = i & 255;
        tile[l][c] = X[((long)b * L + l0 + l) * CDIM + c];
    }
    __syncthreads();
    {
        int l = tid >> 3, sub = tid & 7;
        float s1 = 0.f, s2 = 0.f;
        for (int c = sub * 32; c < sub * 32 + 32; ++c) {
            float v = tile[l][c];
            s1 += v; s2 += v * v;
        }
        s1 += __shfl_xor(s1, 1); s2 += __shfl_xor(s2, 1);
        s1 += __shfl_xor(s1, 2); s2 += __shfl_xor(s2, 2);
        s1 += __shfl_xor(s1, 4); s2 += __shfl_xor(s2, 4);
        if (sub == 0) {
            float mu = s1 * (1.f / 256.f);
            float var = s2 * (1.f / 256.f) - mu * mu;
            sMu[l] = mu;
            sRs[l] = rsqrtf(var + 1e-5f);
        }
    }
    __syncthreads();
    for (int i = tid; i < 32 * 256; i += 256) {
        int ll = i & 31, c = i >> 5;
        float v = (tile[ll][c] - sMu[ll]) * sRs[ll] * gamma[c] + beta[c];
        out[((long)b * CDIM + c) * L + l0 + ll] = v;
    }
}

extern "C" void kernel_launch(void* const* d_in, const int* in_sizes, int n_in,
                              void* d_out, int out_size, void* d_ws, size_t ws_size,
                              hipStream_t stream)
{
    const float* sp   = (const float*)d_in[0];
    const float* fq   = (const float*)d_in[1];
    const float* Wp   = (const float*)d_in[2];
    const float* bp   = (const float*)d_in[3];
    const float* Win  = (const float*)d_in[4];
    const float* cw   = (const float*)d_in[5];
    const float* cb   = (const float*)d_in[6];
    const float* Wx   = (const float*)d_in[7];
    const float* Wdt  = (const float*)d_in[8];
    const float* bdt  = (const float*)d_in[9];
    const float* Alog = (const float*)d_in[10];
    const float* Dp   = (const float*)d_in[11];
    const float* Wout = (const float*)d_in[12];
    const float* gam  = (const float*)d_in[13];
    const float* bet  = (const float*)d_in[14];
    float* out = (float*)d_out;
    float* ws  = (float*)d_ws;

    size_t off = 0;
    float* x_proj = ws + off; off += (size_t)BATCH * L * CDIM;  // reused: Asum/Xsum, then x_mixed
    float* u_pre  = ws + off; off += (size_t)BATCH * L * DIN;   // reused as delta
    float* zb     = ws + off; off += (size_t)BATCH * L * DIN;
    float* ub     = ws + off; off += (size_t)BATCH * L * DIN;
    float* yb     = ws + off; off += (size_t)BATCH * L * DIN;
    float* dtb    = ws + off; off += (size_t)BATCH * L * DTR;
    float* Bmb    = ws + off; off += (size_t)BATCH * L * DSTATE;
    float* Cmb    = ws + off; off += (size_t)BATCH * L * DSTATE;

    // chunk summaries alias x_proj (dead between GEMM2 and GEMM5): exact fit
    float* Asum = x_proj;                                       // B*NC*DIN*16
    float* Xsum = x_proj + (size_t)BATCH * NC * DIN * DSTATE;   // same size

    dim3 blk(256);
    gemm_kernel<EPI_BIAS, true><<<dim3(L / 64, CDIM / 64, BATCH), blk, 0, stream>>>(
        sp, fq, Wp, bp, x_proj, nullptr, nullptr, L, CDIM, 2 * CDIM, CDIM, (long)CDIM * L);
    gemm_kernel<EPI_SPLITUZ, false><<<dim3(L / 64, 2 * DIN / 64, BATCH), blk, 0, stream>>>(
        x_proj, nullptr, Win, nullptr, u_pre, zb, nullptr, L, 2 * DIN, CDIM, 1 << 30, (long)L * CDIM);
    conv_silu_kernel<<<dim3((BATCH * L * DIN) / 256), blk, 0, stream>>>(u_pre, cw, cb, ub);
    gemm_kernel<EPI_DBC, false><<<dim3(L / 64, 1, BATCH), blk, 0, stream>>>(
        ub, nullptr, Wx, nullptr, dtb, Bmb, Cmb, L, 48, DIN, 1 << 30, (long)L * DIN);
    gemm_kernel<EPI_SOFTPLUS, false><<<dim3(L / 64, DIN / 64, BATCH), blk, 0, stream>>>(
        dtb, nullptr, Wdt, bdt, u_pre, nullptr, nullptr, L, DIN, DTR, 1 << 30, (long)L * DTR);

    // parallel scan (delta lives in u_pre)
    scan_phase1<<<dim3(BATCH * NDG * NC), dim3(128), 0, stream>>>(
        u_pre, ub, Bmb, Alog, Asum, Xsum);
    scan_phase2<<<dim3(BATCH * DIN * DSTATE / 256), dim3(256), 0, stream>>>(Asum, Xsum);
    scan_phase3<<<dim3(BATCH * NDG * NC), dim3(128), 0, stream>>>(
        u_pre, ub, Bmb, Cmb, zb, Alog, Dp, Xsum, yb);

    gemm_kernel<EPI_BIAS, false><<<dim3(L / 64, CDIM / 64, BATCH), blk, 0, stream>>>(
        yb, nullptr, Wout, nullptr, x_proj, nullptr, nullptr, L, CDIM, DIN, 1 << 30, (long)L * DIN);
    ln_kernel<<<dim3(L / 32, BATCH), blk, 0, stream>>>(x_proj, gam, bet, out);
}

// Round 3
// 623.521 us; speedup vs baseline: 2.4454x; 1.1784x over previous
//
#include <hip/hip_runtime.h>
#include <math.h>

#define L 4096
#define CDIM 256
#define DIN 512
#define DSTATE 16
#define DTR 16
#define BATCH 4

__device__ __forceinline__ float silu_f(float x) { return x / (1.f + __expf(-x)); }
__device__ __forceinline__ float softplus_f(float x) {
    return (x > 20.f) ? x : log1pf(__expf(x));
}

// ---------------- generic tiled fp32 GEMM ----------------
enum { EPI_BIAS = 0, EPI_SPLITUZ = 1, EPI_DBC = 2, EPI_SOFTPLUS = 3 };

template<int EPI, bool A_KMAJOR>
__global__ __launch_bounds__(256)
void gemm_kernel(const float* __restrict__ A0, const float* __restrict__ A1,
                 const float* __restrict__ Wt, const float* __restrict__ bias,
                 float* __restrict__ O0, float* __restrict__ O1, float* __restrict__ O2,
                 int M, int N, int K, int kSplit, long strideAb)
{
    __shared__ float As[16][68];
    __shared__ float Ws[16][68];
    const int b  = blockIdx.z;
    const int m0 = blockIdx.x * 64;
    const int n0 = blockIdx.y * 64;
    const int tid = threadIdx.x;
    const int tn = tid & 15, tm = tid >> 4;
    float acc[4][4] = {};
    for (int k0 = 0; k0 < K; k0 += 16) {
        if (A_KMAJOR) {
            int m = tid & 63, kk = tid >> 6;
            #pragma unroll
            for (int p = 0; p < 4; ++p) {
                int k = kk + p * 4;
                int kg = k0 + k;
                const float* Ap = (kg < kSplit) ? A0 : A1;
                int kl = (kg < kSplit) ? kg : (kg - kSplit);
                As[k][m] = Ap[(long)b * strideAb + (long)kl * M + (m0 + m)];
            }
        } else {
            int k = tid & 15, mm = tid >> 4;
            #pragma unroll
            for (int p = 0; p < 4; ++p) {
                int m = mm + p * 16;
                As[k][m] = A0[(long)b * strideAb + (long)(m0 + m) * K + (k0 + k)];
            }
        }
        {
            int k = tid & 15, nn = tid >> 4;
            #pragma unroll
            for (int p = 0; p < 4; ++p) {
                int n = nn + p * 16;
                float v = 0.f;
                if (n0 + n < N) v = Wt[(long)(n0 + n) * K + (k0 + k)];
                Ws[k][n] = v;
            }
        }
        __syncthreads();
        #pragma unroll
        for (int k = 0; k < 16; ++k) {
            float4 a = *(const float4*)&As[k][tm * 4];
            float4 w = *(const float4*)&Ws[k][tn * 4];
            float av[4] = {a.x, a.y, a.z, a.w};
            float wv[4] = {w.x, w.y, w.z, w.w};
            #pragma unroll
            for (int i = 0; i < 4; ++i)
                #pragma unroll
                for (int j = 0; j < 4; ++j)
                    acc[i][j] += av[i] * wv[j];
        }
        __syncthreads();
    }
    #pragma unroll
    for (int i = 0; i < 4; ++i) {
        int m = m0 + tm * 4 + i;
        long rowb = (long)b * M + m;
        #pragma unroll
        for (int j = 0; j < 4; ++j) {
            int n = n0 + tn * 4 + j;
            if (n >= N) continue;
            float v = acc[i][j];
            if (EPI == EPI_BIAS) {
                if (bias) v += bias[n];
                O0[rowb * N + n] = v;
            } else if (EPI == EPI_SPLITUZ) {
                if (n < DIN) O0[rowb * DIN + n] = v;
                else         O1[rowb * DIN + (n - DIN)] = v;
            } else if (EPI == EPI_DBC) {
                if (n < 16)      O0[rowb * 16 + n] = v;
                else if (n < 32) O1[rowb * 16 + (n - 16)] = v;
                else             O2[rowb * 16 + (n - 32)] = v;
            } else if (EPI == EPI_SOFTPLUS) {
                v += bias[n];
                O0[rowb * N + n] = softplus_f(v);
            }
        }
    }
}

// ---------------- depthwise causal conv (k=4) + silu ----------------
__global__ __launch_bounds__(256)
void conv_silu_kernel(const float* __restrict__ u_pre, const float* __restrict__ cw,
                      const float* __restrict__ cb, float* __restrict__ u)
{
    long idx = (long)blockIdx.x * blockDim.x + threadIdx.x;
    int d = (int)(idx % DIN);
    long bl = idx / DIN;
    int l = (int)(bl % L);
    long brow = bl - l;
    float v = cb[d];
    #pragma unroll
    for (int j = 0; j < 4; ++j) {
        int li = l - 3 + j;
        if (li >= 0) v += u_pre[(brow + li) * DIN + d] * cw[d * 4 + j];
    }
    u[idx] = silu_f(v);
}

// ---------------- chunked parallel selective scan, d-per-lane ----------------
// h[t] = a[t]*h[t-1] + x[t], a = exp(delta*A), x = delta*u*B.
// One lane owns one d and holds h[16] (all states) in registers:
//   no shuffles, y-reduction is an in-register FMA chain over s.
#define NC 128
#define LC (L / NC)          // 32 steps per chunk

__global__ __launch_bounds__(256)
void scan_phase1(const float* __restrict__ delta, const float* __restrict__ u,
                 const float* __restrict__ Bm, const float* __restrict__ A_log,
                 float* __restrict__ Asum, float* __restrict__ Xsum)
{
    __shared__ float sB[LC][DSTATE];
    const int gd = blockIdx.x & 1;
    const int c  = (blockIdx.x >> 1) & (NC - 1);
    const int b  = blockIdx.x >> 8;            // / (2*NC)
    const int d  = gd * 256 + threadIdx.x;
    const int t0 = c * LC;
    float Arow[DSTATE];
    #pragma unroll
    for (int q = 0; q < 4; ++q) {
        float4 v = *(const float4*)&A_log[d * DSTATE + q * 4];
        Arow[q * 4 + 0] = -__expf(v.x);
        Arow[q * 4 + 1] = -__expf(v.y);
        Arow[q * 4 + 2] = -__expf(v.z);
        Arow[q * 4 + 3] = -__expf(v.w);
    }
    for (int i = threadIdx.x; i < LC * DSTATE; i += 256)
        sB[i >> 4][i & 15] = Bm[((long)b * L + t0 + (i >> 4)) * DSTATE + (i & 15)];
    __syncthreads();
    float P[DSTATE], X[DSTATE];
    #pragma unroll
    for (int s = 0; s < DSTATE; ++s) { P[s] = 1.f; X[s] = 0.f; }
    for (int t = 0; t < LC; ++t) {
        long gidx = ((long)b * L + t0 + t) * DIN + d;
        float dlt = delta[gidx];
        float du  = dlt * u[gidx];
        #pragma unroll
        for (int s = 0; s < DSTATE; ++s) {
            float a = __expf(dlt * Arow[s]);
            P[s] *= a;
            X[s] = a * X[s] + du * sB[t][s];
        }
    }
    long o = (((long)b * NC + c) * DIN + d) * DSTATE;
    #pragma unroll
    for (int q = 0; q < 4; ++q) {
        *(float4*)&Asum[o + q * 4] = make_float4(P[q*4], P[q*4+1], P[q*4+2], P[q*4+3]);
        *(float4*)&Xsum[o + q * 4] = make_float4(X[q*4], X[q*4+1], X[q*4+2], X[q*4+3]);
    }
}

__global__ __launch_bounds__(256)
void scan_phase2(const float* __restrict__ Asum, float* __restrict__ Xsum)
{
    int lane = blockIdx.x * 256 + threadIdx.x;       // (b*DIN + d)*16 + s
    int b = lane / (DIN * DSTATE);
    int rem = lane % (DIN * DSTATE);
    float h = 0.f;
    for (int c = 0; c < NC; ++c) {
        long idx = ((long)b * NC + c) * (DIN * DSTATE) + rem;
        float A = Asum[idx], X = Xsum[idx];
        Xsum[idx] = h;                               // h at START of chunk c
        h = A * h + X;
    }
}

__global__ __launch_bounds__(256)
void scan_phase3(const float* __restrict__ delta, const float* __restrict__ u,
                 const float* __restrict__ Bm, const float* __restrict__ Cm,
                 const float* __restrict__ z, const float* __restrict__ A_log,
                 const float* __restrict__ Dp, const float* __restrict__ Hinit,
                 float* __restrict__ y2)
{
    __shared__ float sB[LC][DSTATE], sC[LC][DSTATE];
    const int gd = blockIdx.x & 1;
    const int c  = (blockIdx.x >> 1) & (NC - 1);
    const int b  = blockIdx.x >> 8;
    const int d  = gd * 256 + threadIdx.x;
    const int t0 = c * LC;
    float Arow[DSTATE];
    #pragma unroll
    for (int q = 0; q < 4; ++q) {
        float4 v = *(const float4*)&A_log[d * DSTATE + q * 4];
        Arow[q * 4 + 0] = -__expf(v.x);
        Arow[q * 4 + 1] = -__expf(v.y);
        Arow[q * 4 + 2] = -__expf(v.z);
        Arow[q * 4 + 3] = -__expf(v.w);
    }
    for (int i = threadIdx.x; i < LC * DSTATE; i += 256) {
        long gidx = ((long)b * L + t0 + (i >> 4)) * DSTATE + (i & 15);
        sB[i >> 4][i & 15] = Bm[gidx];
        sC[i >> 4][i & 15] = Cm[gidx];
    }
    float h[DSTATE];
    {
        long o = (((long)b * NC + c) * DIN + d) * DSTATE;
        #pragma unroll
        for (int q = 0; q < 4; ++q) {
            float4 v = *(const float4*)&Hinit[o + q * 4];
            h[q * 4 + 0] = v.x; h[q * 4 + 1] = v.y;
            h[q * 4 + 2] = v.z; h[q * 4 + 3] = v.w;
        }
    }
    const float Dval = Dp[d];
    __syncthreads();
    for (int t = 0; t < LC; ++t) {
        long gidx = ((long)b * L + t0 + t) * DIN + d;
        float dlt = delta[gidx];
        float uu  = u[gidx];
        float zz  = z[gidx];
        float du  = dlt * uu;
        float y = 0.f;
        #pragma unroll
        for (int s = 0; s < DSTATE; ++s) {
            float a = __expf(dlt * Arow[s]);
            h[s] = h[s] * a + du * sB[t][s];
            y += h[s] * sC[t][s];
        }
        y2[gidx] = (y + uu * Dval) * silu_f(zz);
    }
}

// ---------------- LayerNorm over C + transpose to (B,C,L) ----------------
__global__ __launch_bounds__(256)
void ln_kernel(const float* __restrict__ X, const float* __restrict__ gamma,
               const float* __restrict__ beta, float* __restrict__ out)
{
    __shared__ float tile[32][257];
    __shared__ float sMu[32], sRs[32];
    const int l0 = blockIdx.x * 32;
    const int b  = blockIdx.y;
    const int tid = threadIdx.x;
    for (int i = tid; i < 32 * 256; i += 256) {
        int l = i >> 8, c = i & 255;
        tile[l][c] = X[((long)b * L + l0 + l) * CDIM + c];
    }
    __syncthreads();
    {
        int l = tid >> 3, sub = tid & 7;
        float s1 = 0.f, s2 = 0.f;
        for (int c = sub * 32; c < sub * 32 + 32; ++c) {
            float v = tile[l][c];
            s1 += v; s2 += v * v;
        }
        s1 += __shfl_xor(s1, 1); s2 += __shfl_xor(s2, 1);
        s1 += __shfl_xor(s1, 2); s2 += __shfl_xor(s2, 2);
        s1 += __shfl_xor(s1, 4); s2 += __shfl_xor(s2, 4);
        if (sub == 0) {
            float mu = s1 * (1.f / 256.f);
            float var = s2 * (1.f / 256.f) - mu * mu;
            sMu[l] = mu;
            sRs[l] = rsqrtf(var + 1e-5f);
        }
    }
    __syncthreads();
    for (int i = tid; i < 32 * 256; i += 256) {
        int ll = i & 31, c = i >> 5;
        float v = (tile[ll][c] - sMu[ll]) * sRs[ll] * gamma[c] + beta[c];
        out[((long)b * CDIM + c) * L + l0 + ll] = v;
    }
}

extern "C" void kernel_launch(void* const* d_in, const int* in_sizes, int n_in,
                              void* d_out, int out_size, void* d_ws, size_t ws_size,
                              hipStream_t stream)
{
    const float* sp   = (const float*)d_in[0];
    const float* fq   = (const float*)d_in[1];
    const float* Wp   = (const float*)d_in[2];
    const float* bp   = (const float*)d_in[3];
    const float* Win  = (const float*)d_in[4];
    const float* cw   = (const float*)d_in[5];
    const float* cb   = (const float*)d_in[6];
    const float* Wx   = (const float*)d_in[7];
    const float* Wdt  = (const float*)d_in[8];
    const float* bdt  = (const float*)d_in[9];
    const float* Alog = (const float*)d_in[10];
    const float* Dp   = (const float*)d_in[11];
    const float* Wout = (const float*)d_in[12];
    const float* gam  = (const float*)d_in[13];
    const float* bet  = (const float*)d_in[14];
    float* out = (float*)d_out;
    float* ws  = (float*)d_ws;

    size_t off = 0;
    float* x_proj = ws + off; off += (size_t)BATCH * L * CDIM;  // reused: Asum/Xsum, then x_mixed
    float* u_pre  = ws + off; off += (size_t)BATCH * L * DIN;   // reused as delta
    float* zb     = ws + off; off += (size_t)BATCH * L * DIN;
    float* ub     = ws + off; off += (size_t)BATCH * L * DIN;
    float* yb     = ws + off; off += (size_t)BATCH * L * DIN;
    float* dtb    = ws + off; off += (size_t)BATCH * L * DTR;
    float* Bmb    = ws + off; off += (size_t)BATCH * L * DSTATE;
    float* Cmb    = ws + off; off += (size_t)BATCH * L * DSTATE;

    // chunk summaries alias x_proj (dead between GEMM2 and GEMM5):
    // 2 * B*NC*DIN*16 = 8.4M floats <= B*L*CDIM = 16.8M floats
    float* Asum = x_proj;
    float* Xsum = x_proj + (size_t)BATCH * NC * DIN * DSTATE;

    dim3 blk(256);
    gemm_kernel<EPI_BIAS, true><<<dim3(L / 64, CDIM / 64, BATCH), blk, 0, stream>>>(
        sp, fq, Wp, bp, x_proj, nullptr, nullptr, L, CDIM, 2 * CDIM, CDIM, (long)CDIM * L);
    gemm_kernel<EPI_SPLITUZ, false><<<dim3(L / 64, 2 * DIN / 64, BATCH), blk, 0, stream>>>(
        x_proj, nullptr, Win, nullptr, u_pre, zb, nullptr, L, 2 * DIN, CDIM, 1 << 30, (long)L * CDIM);
    conv_silu_kernel<<<dim3((BATCH * L * DIN) / 256), blk, 0, stream>>>(u_pre, cw, cb, ub);
    gemm_kernel<EPI_DBC, false><<<dim3(L / 64, 1, BATCH), blk, 0, stream>>>(
        ub, nullptr, Wx, nullptr, dtb, Bmb, Cmb, L, 48, DIN, 1 << 30, (long)L * DIN);
    gemm_kernel<EPI_SOFTPLUS, false><<<dim3(L / 64, DIN / 64, BATCH), blk, 0, stream>>>(
        dtb, nullptr, Wdt, bdt, u_pre, nullptr, nullptr, L, DIN, DTR, 1 << 30, (long)L * DTR);

    // parallel scan (delta lives in u_pre)
    scan_phase1<<<dim3(BATCH * NC * 2), blk, 0, stream>>>(u_pre, ub, Bmb, Alog, Asum, Xsum);
    scan_phase2<<<dim3(BATCH * DIN * DSTATE / 256), blk, 0, stream>>>(Asum, Xsum);
    scan_phase3<<<dim3(BATCH * NC * 2), blk, 0, stream>>>(
        u_pre, ub, Bmb, Cmb, zb, Alog, Dp, Xsum, yb);

    gemm_kernel<EPI_BIAS, false><<<dim3(L / 64, CDIM / 64, BATCH), blk, 0, stream>>>(
        yb, nullptr, Wout, nullptr, x_proj, nullptr, nullptr, L, CDIM, DIN, 1 << 30, (long)L * DIN);
    ln_kernel<<<dim3(L / 32, BATCH), blk, 0, stream>>>(x_proj, gam, bet, out);
}

// Round 4
// 433.924 us; speedup vs baseline: 3.5139x; 1.4369x over previous
//
#include <hip/hip_runtime.h>
#include <math.h>

#define L 4096
#define CDIM 256
#define DIN 512
#define DSTATE 16
#define DTR 16
#define BATCH 4

using f32x4  = __attribute__((ext_vector_type(4))) float;
using bf16x8 = __attribute__((ext_vector_type(8))) __bf16;

__device__ __forceinline__ float silu_f(float x) { return x / (1.f + __expf(-x)); }
__device__ __forceinline__ float softplus_f(float x) {
    return (x > 20.f) ? x : log1pf(__expf(x));
}

// split fp32 -> (hi, lo) bf16 planes, packed pairwise into uints.
// hi = truncate-to-bf16(x), lo = truncate-to-bf16(x - hi).  x ~= hi + lo, resid ~2^-17|x|
__device__ __forceinline__ void split_pack2(float x0, float x1, unsigned &h, unsigned &l) {
    unsigned b0 = __float_as_uint(x0), b1 = __float_as_uint(x1);
    h = (b0 >> 16) | (b1 & 0xffff0000u);
    float l0 = x0 - __uint_as_float(b0 & 0xffff0000u);
    float l1 = x1 - __uint_as_float(b1 & 0xffff0000u);
    l = (__float_as_uint(l0) >> 16) | (__float_as_uint(l1) & 0xffff0000u);
}

enum { EPI_BIAS = 0, EPI_SPLITUZ = 1, EPI_DBC = 2, EPI_SOFTPLUS = 3 };

// ---------------- split-bf16 MFMA GEMM ----------------
// Out[b,m,n] = sum_k A[b,m,k] * Wt[n,k]  via (ah+al)x(bh+bl) ~ ah*bh + ah*bl + al*bh
// Block tile: M=128, N=64, K-step 32. 4 waves; wave w does rows [32w,32w+32) x all 64 n.
// LDS fragment-linear: Xh[oct][row][8] so each lane's 8 contiguous bf16 = 1 ds_read_b128.
template<int EPI, bool A_KMAJOR>
__global__ __launch_bounds__(256)
void mfma_gemm(const float* __restrict__ A0, const float* __restrict__ A1,
               const float* __restrict__ Wt, const float* __restrict__ bias,
               float* __restrict__ O0, float* __restrict__ O1,
               int M, int N, int K, int kSplit, long strideAb)
{
    __shared__ __align__(16) unsigned short Ah[4][128][8], Al[4][128][8];
    __shared__ __align__(16) unsigned short Bh[4][64][8],  Bl[4][64][8];
    const int b  = blockIdx.z;
    const int n0 = blockIdx.x * 64;
    const int m0 = blockIdx.y * 128;
    const int tid  = threadIdx.x;
    const int lane = tid & 63;
    const int w    = tid >> 6;
    const int lrow = lane & 15;
    const int loct = lane >> 4;

    f32x4 acc[2][4];
    #pragma unroll
    for (int i = 0; i < 2; ++i)
        #pragma unroll
        for (int j = 0; j < 4; ++j)
            acc[i][j] = (f32x4){0.f, 0.f, 0.f, 0.f};

    for (int kk = 0; kk < K; kk += 32) {
        // ---- stage A (128 x 32) ----
        if (A_KMAJOR) {
            int m = tid & 127, half = tid >> 7;
            float v[16];
            #pragma unroll
            for (int j = 0; j < 16; ++j) {
                int kg = kk + half * 16 + j;
                const float* Ap; int kl;
                if (kg < kSplit) { Ap = A0; kl = kg; } else { Ap = A1; kl = kg - kSplit; }
                v[j] = Ap[(long)b * strideAb + (long)kl * M + m0 + m];
            }
            #pragma unroll
            for (int o = 0; o < 2; ++o) {
                uint4 h, l;
                split_pack2(v[o*8+0], v[o*8+1], h.x, l.x);
                split_pack2(v[o*8+2], v[o*8+3], h.y, l.y);
                split_pack2(v[o*8+4], v[o*8+5], h.z, l.z);
                split_pack2(v[o*8+6], v[o*8+7], h.w, l.w);
                *(uint4*)&Ah[half*2+o][m][0] = h;
                *(uint4*)&Al[half*2+o][m][0] = l;
            }
        } else {
            int oct = tid & 3, mA = tid >> 2;
            #pragma unroll
            for (int p = 0; p < 2; ++p) {
                int m = mA + p * 64;
                const float* g = A0 + (long)b * strideAb + (long)(m0 + m) * K + kk + oct * 8;
                float4 x0 = *(const float4*)g;
                float4 x1 = *(const float4*)(g + 4);
                uint4 h, l;
                split_pack2(x0.x, x0.y, h.x, l.x);
                split_pack2(x0.z, x0.w, h.y, l.y);
                split_pack2(x1.x, x1.y, h.z, l.z);
                split_pack2(x1.z, x1.w, h.w, l.w);
                *(uint4*)&Ah[oct][m][0] = h;
                *(uint4*)&Al[oct][m][0] = l;
            }
        }
        // ---- stage B (64 x 32) from Wt[n][k] row-major ----
        {
            int oct = tid & 3, n = tid >> 2;
            const float* g = Wt + (long)(n0 + n) * K + kk + oct * 8;
            float4 x0 = *(const float4*)g;
            float4 x1 = *(const float4*)(g + 4);
            uint4 h, l;
            split_pack2(x0.x, x0.y, h.x, l.x);
            split_pack2(x0.z, x0.w, h.y, l.y);
            split_pack2(x1.x, x1.y, h.z, l.z);
            split_pack2(x1.z, x1.w, h.w, l.w);
            *(uint4*)&Bh[oct][n][0] = h;
            *(uint4*)&Bl[oct][n][0] = l;
        }
        __syncthreads();
        // ---- MFMA ----
        bf16x8 ah[2], al2[2], bh[4], bl2[4];
        #pragma unroll
        for (int mt = 0; mt < 2; ++mt) {
            ah[mt]  = *(const bf16x8*)&Ah[loct][w*32 + mt*16 + lrow][0];
            al2[mt] = *(const bf16x8*)&Al[loct][w*32 + mt*16 + lrow][0];
        }
        #pragma unroll
        for (int nt = 0; nt < 4; ++nt) {
            bh[nt]  = *(const bf16x8*)&Bh[loct][nt*16 + lrow][0];
            bl2[nt] = *(const bf16x8*)&Bl[loct][nt*16 + lrow][0];
        }
        #pragma unroll
        for (int mt = 0; mt < 2; ++mt)
            #pragma unroll
            for (int nt = 0; nt < 4; ++nt) {
                acc[mt][nt] = __builtin_amdgcn_mfma_f32_16x16x32_bf16(ah[mt],  bh[nt],  acc[mt][nt], 0, 0, 0);
                acc[mt][nt] = __builtin_amdgcn_mfma_f32_16x16x32_bf16(ah[mt],  bl2[nt], acc[mt][nt], 0, 0, 0);
                acc[mt][nt] = __builtin_amdgcn_mfma_f32_16x16x32_bf16(al2[mt], bh[nt],  acc[mt][nt], 0, 0, 0);
            }
        __syncthreads();
    }
    // ---- epilogue: C/D col=lane&15, row=(lane>>4)*4+reg ----
    #pragma unroll
    for (int mt = 0; mt < 2; ++mt) {
        #pragma unroll
        for (int r = 0; r < 4; ++r) {
            int m = m0 + w * 32 + mt * 16 + loct * 4 + r;
            long rowb = (long)b * M + m;
            #pragma unroll
            for (int nt = 0; nt < 4; ++nt) {
                int n = n0 + nt * 16 + lrow;
                float v = acc[mt][nt][r];
                if (EPI == EPI_BIAS) {
                    if (bias) v += bias[n];
                    O0[rowb * N + n] = v;
                } else if (EPI == EPI_SPLITUZ) {
                    if (n < DIN) O0[rowb * DIN + n] = v;
                    else         O1[rowb * DIN + (n - DIN)] = v;
                }
            }
        }
    }
}

// ---------------- small fp32 vector GEMM (GEMM3/GEMM4: delta path stays exact) ----------------
template<int EPI>
__global__ __launch_bounds__(256)
void gemm_kernel(const float* __restrict__ A0,
                 const float* __restrict__ Wt, const float* __restrict__ bias,
                 float* __restrict__ O0, float* __restrict__ O1, float* __restrict__ O2,
                 int M, int N, int K, long strideAb)
{
    __shared__ float As[16][68];
    __shared__ float Ws[16][68];
    const int b  = blockIdx.z;
    const int m0 = blockIdx.x * 64;
    const int n0 = blockIdx.y * 64;
    const int tid = threadIdx.x;
    const int tn = tid & 15, tm = tid >> 4;
    float acc[4][4] = {};
    for (int k0 = 0; k0 < K; k0 += 16) {
        {
            int k = tid & 15, mm = tid >> 4;
            #pragma unroll
            for (int p = 0; p < 4; ++p) {
                int m = mm + p * 16;
                As[k][m] = A0[(long)b * strideAb + (long)(m0 + m) * K + (k0 + k)];
            }
        }
        {
            int k = tid & 15, nn = tid >> 4;
            #pragma unroll
            for (int p = 0; p < 4; ++p) {
                int n = nn + p * 16;
                float v = 0.f;
                if (n0 + n < N) v = Wt[(long)(n0 + n) * K + (k0 + k)];
                Ws[k][n] = v;
            }
        }
        __syncthreads();
        #pragma unroll
        for (int k = 0; k < 16; ++k) {
            float4 a = *(const float4*)&As[k][tm * 4];
            float4 wv4 = *(const float4*)&Ws[k][tn * 4];
            float av[4] = {a.x, a.y, a.z, a.w};
            float wv[4] = {wv4.x, wv4.y, wv4.z, wv4.w};
            #pragma unroll
            for (int i = 0; i < 4; ++i)
                #pragma unroll
                for (int j = 0; j < 4; ++j)
                    acc[i][j] += av[i] * wv[j];
        }
        __syncthreads();
    }
    #pragma unroll
    for (int i = 0; i < 4; ++i) {
        int m = m0 + tm * 4 + i;
        long rowb = (long)b * M + m;
        #pragma unroll
        for (int j = 0; j < 4; ++j) {
            int n = n0 + tn * 4 + j;
            if (n >= N) continue;
            float v = acc[i][j];
            if (EPI == EPI_DBC) {
                if (n < 16)      O0[rowb * 16 + n] = v;
                else if (n < 32) O1[rowb * 16 + (n - 16)] = v;
                else             O2[rowb * 16 + (n - 32)] = v;
            } else if (EPI == EPI_SOFTPLUS) {
                v += bias[n];
                O0[rowb * N + n] = softplus_f(v);
            }
        }
    }
}

// ---------------- depthwise causal conv (k=4) + silu ----------------
__global__ __launch_bounds__(256)
void conv_silu_kernel(const float* __restrict__ u_pre, const float* __restrict__ cw,
                      const float* __restrict__ cb, float* __restrict__ u)
{
    long idx = (long)blockIdx.x * blockDim.x + threadIdx.x;
    int d = (int)(idx % DIN);
    long bl = idx / DIN;
    int l = (int)(bl % L);
    long brow = bl - l;
    float v = cb[d];
    #pragma unroll
    for (int j = 0; j < 4; ++j) {
        int li = l - 3 + j;
        if (li >= 0) v += u_pre[(brow + li) * DIN + d] * cw[d * 4 + j];
    }
    u[idx] = silu_f(v);
}

// ---------------- chunked parallel selective scan, d-per-lane ----------------
#define NC 128
#define LC (L / NC)

__global__ __launch_bounds__(256)
void scan_phase1(const float* __restrict__ delta, const float* __restrict__ u,
                 const float* __restrict__ Bm, const float* __restrict__ A_log,
                 float* __restrict__ Asum, float* __restrict__ Xsum)
{
    __shared__ float sB[LC][DSTATE];
    const int gd = blockIdx.x & 1;
    const int c  = (blockIdx.x >> 1) & (NC - 1);
    const int b  = blockIdx.x >> 8;
    const int d  = gd * 256 + threadIdx.x;
    const int t0 = c * LC;
    float Arow[DSTATE];
    #pragma unroll
    for (int q = 0; q < 4; ++q) {
        float4 v = *(const float4*)&A_log[d * DSTATE + q * 4];
        Arow[q * 4 + 0] = -__expf(v.x);
        Arow[q * 4 + 1] = -__expf(v.y);
        Arow[q * 4 + 2] = -__expf(v.z);
        Arow[q * 4 + 3] = -__expf(v.w);
    }
    for (int i = threadIdx.x; i < LC * DSTATE; i += 256)
        sB[i >> 4][i & 15] = Bm[((long)b * L + t0 + (i >> 4)) * DSTATE + (i & 15)];
    __syncthreads();
    float P[DSTATE], X[DSTATE];
    #pragma unroll
    for (int s = 0; s < DSTATE; ++s) { P[s] = 1.f; X[s] = 0.f; }
    for (int t = 0; t < LC; ++t) {
        long gidx = ((long)b * L + t0 + t) * DIN + d;
        float dlt = delta[gidx];
        float du  = dlt * u[gidx];
        #pragma unroll
        for (int s = 0; s < DSTATE; ++s) {
            float a = __expf(dlt * Arow[s]);
            P[s] *= a;
            X[s] = a * X[s] + du * sB[t][s];
        }
    }
    long o = (((long)b * NC + c) * DIN + d) * DSTATE;
    #pragma unroll
    for (int q = 0; q < 4; ++q) {
        *(float4*)&Asum[o + q * 4] = make_float4(P[q*4], P[q*4+1], P[q*4+2], P[q*4+3]);
        *(float4*)&Xsum[o + q * 4] = make_float4(X[q*4], X[q*4+1], X[q*4+2], X[q*4+3]);
    }
}

__global__ __launch_bounds__(256)
void scan_phase2(const float* __restrict__ Asum, float* __restrict__ Xsum)
{
    int lane = blockIdx.x * 256 + threadIdx.x;
    int b = lane / (DIN * DSTATE);
    int rem = lane % (DIN * DSTATE);
    float h = 0.f;
    for (int c = 0; c < NC; ++c) {
        long idx = ((long)b * NC + c) * (DIN * DSTATE) + rem;
        float A = Asum[idx], X = Xsum[idx];
        Xsum[idx] = h;
        h = A * h + X;
    }
}

__global__ __launch_bounds__(256)
void scan_phase3(const float* __restrict__ delta, const float* __restrict__ u,
                 const float* __restrict__ Bm, const float* __restrict__ Cm,
                 const float* __restrict__ z, const float* __restrict__ A_log,
                 const float* __restrict__ Dp, const float* __restrict__ Hinit,
                 float* __restrict__ y2)
{
    __shared__ float sB[LC][DSTATE], sC[LC][DSTATE];
    const int gd = blockIdx.x & 1;
    const int c  = (blockIdx.x >> 1) & (NC - 1);
    const int b  = blockIdx.x >> 8;
    const int d  = gd * 256 + threadIdx.x;
    const int t0 = c * LC;
    float Arow[DSTATE];
    #pragma unroll
    for (int q = 0; q < 4; ++q) {
        float4 v = *(const float4*)&A_log[d * DSTATE + q * 4];
        Arow[q * 4 + 0] = -__expf(v.x);
        Arow[q * 4 + 1] = -__expf(v.y);
        Arow[q * 4 + 2] = -__expf(v.z);
        Arow[q * 4 + 3] = -__expf(v.w);
    }
    for (int i = threadIdx.x; i < LC * DSTATE; i += 256) {
        long gidx = ((long)b * L + t0 + (i >> 4)) * DSTATE + (i & 15);
        sB[i >> 4][i & 15] = Bm[gidx];
        sC[i >> 4][i & 15] = Cm[gidx];
    }
    float h[DSTATE];
    {
        long o = (((long)b * NC + c) * DIN + d) * DSTATE;
        #pragma unroll
        for (int q = 0; q < 4; ++q) {
            float4 v = *(const float4*)&Hinit[o + q * 4];
            h[q * 4 + 0] = v.x; h[q * 4 + 1] = v.y;
            h[q * 4 + 2] = v.z; h[q * 4 + 3] = v.w;
        }
    }
    const float Dval = Dp[d];
    __syncthreads();
    for (int t = 0; t < LC; ++t) {
        long gidx = ((long)b * L + t0 + t) * DIN + d;
        float dlt = delta[gidx];
        float uu  = u[gidx];
        float zz  = z[gidx];
        float du  = dlt * uu;
        float y = 0.f;
        #pragma unroll
        for (int s = 0; s < DSTATE; ++s) {
            float a = __expf(dlt * Arow[s]);
            h[s] = h[s] * a + du * sB[t][s];
            y += h[s] * sC[t][s];
        }
        y2[gidx] = (y + uu * Dval) * silu_f(zz);
    }
}

// ---------------- LayerNorm over C + transpose to (B,C,L) ----------------
__global__ __launch_bounds__(256)
void ln_kernel(const float* __restrict__ X, const float* __restrict__ gamma,
               const float* __restrict__ beta, float* __restrict__ out)
{
    __shared__ float tile[32][257];
    __shared__ float sMu[32], sRs[32];
    const int l0 = blockIdx.x * 32;
    const int b  = blockIdx.y;
    const int tid = threadIdx.x;
    for (int i = tid; i < 32 * 256; i += 256) {
        int l = i >> 8, c = i & 255;
        tile[l][c] = X[((long)b * L + l0 + l) * CDIM + c];
    }
    __syncthreads();
    {
        int l = tid >> 3, sub = tid & 7;
        float s1 = 0.f, s2 = 0.f;
        for (int c = sub * 32; c < sub * 32 + 32; ++c) {
            float v = tile[l][c];
            s1 += v; s2 += v * v;
        }
        s1 += __shfl_xor(s1, 1); s2 += __shfl_xor(s2, 1);
        s1 += __shfl_xor(s1, 2); s2 += __shfl_xor(s2, 2);
        s1 += __shfl_xor(s1, 4); s2 += __shfl_xor(s2, 4);
        if (sub == 0) {
            float mu = s1 * (1.f / 256.f);
            float var = s2 * (1.f / 256.f) - mu * mu;
            sMu[l] = mu;
            sRs[l] = rsqrtf(var + 1e-5f);
        }
    }
    __syncthreads();
    for (int i = tid; i < 32 * 256; i += 256) {
        int ll = i & 31, c = i >> 5;
        float v = (tile[ll][c] - sMu[ll]) * sRs[ll] * gamma[c] + beta[c];
        out[((long)b * CDIM + c) * L + l0 + ll] = v;
    }
}

extern "C" void kernel_launch(void* const* d_in, const int* in_sizes, int n_in,
                              void* d_out, int out_size, void* d_ws, size_t ws_size,
                              hipStream_t stream)
{
    const float* sp   = (const float*)d_in[0];
    const float* fq   = (const float*)d_in[1];
    const float* Wp   = (const float*)d_in[2];
    const float* bp   = (const float*)d_in[3];
    const float* Win  = (const float*)d_in[4];
    const float* cw   = (const float*)d_in[5];
    const float* cb   = (const float*)d_in[6];
    const float* Wx   = (const float*)d_in[7];
    const float* Wdt  = (const float*)d_in[8];
    const float* bdt  = (const float*)d_in[9];
    const float* Alog = (const float*)d_in[10];
    const float* Dp   = (const float*)d_in[11];
    const float* Wout = (const float*)d_in[12];
    const float* gam  = (const float*)d_in[13];
    const float* bet  = (const float*)d_in[14];
    float* out = (float*)d_out;
    float* ws  = (float*)d_ws;

    size_t off = 0;
    float* x_proj = ws + off; off += (size_t)BATCH * L * CDIM;  // reused: Asum/Xsum, then x_mixed
    float* u_pre  = ws + off; off += (size_t)BATCH * L * DIN;   // reused as delta
    float* zb     = ws + off; off += (size_t)BATCH * L * DIN;
    float* ub     = ws + off; off += (size_t)BATCH * L * DIN;
    float* yb     = ws + off; off += (size_t)BATCH * L * DIN;
    float* dtb    = ws + off; off += (size_t)BATCH * L * DTR;
    float* Bmb    = ws + off; off += (size_t)BATCH * L * DSTATE;
    float* Cmb    = ws + off; off += (size_t)BATCH * L * DSTATE;

    float* Asum = x_proj;
    float* Xsum = x_proj + (size_t)BATCH * NC * DIN * DSTATE;

    dim3 blk(256);
    // GEMM1 (MFMA split-bf16): x_proj = x_cat @ Wp^T + bp   (A K-major, split at k=256)
    mfma_gemm<EPI_BIAS, true><<<dim3(CDIM / 64, L / 128, BATCH), blk, 0, stream>>>(
        sp, fq, Wp, bp, x_proj, nullptr, L, CDIM, 2 * CDIM, CDIM, (long)CDIM * L);
    // GEMM2 (MFMA): xz = x_proj @ Win^T -> split u_pre / z
    mfma_gemm<EPI_SPLITUZ, false><<<dim3(2 * DIN / 64, L / 128, BATCH), blk, 0, stream>>>(
        x_proj, nullptr, Win, nullptr, u_pre, zb, L, 2 * DIN, CDIM, 1 << 30, (long)L * CDIM);
    conv_silu_kernel<<<dim3((BATCH * L * DIN) / 256), blk, 0, stream>>>(u_pre, cw, cb, ub);
    // GEMM3 (fp32 vector, exact): dbc = u @ Wx^T -> split dt / Bm / Cm
    gemm_kernel<EPI_DBC><<<dim3(L / 64, 1, BATCH), blk, 0, stream>>>(
        ub, Wx, nullptr, dtb, Bmb, Cmb, L, 48, DIN, (long)L * DIN);
    // GEMM4 (fp32 vector, exact): delta = softplus(dt @ Wdt^T + bdt)
    gemm_kernel<EPI_SOFTPLUS><<<dim3(L / 64, DIN / 64, BATCH), blk, 0, stream>>>(
        dtb, Wdt, bdt, u_pre, nullptr, nullptr, L, DIN, DTR, (long)L * DTR);

    scan_phase1<<<dim3(BATCH * NC * 2), blk, 0, stream>>>(u_pre, ub, Bmb, Alog, Asum, Xsum);
    scan_phase2<<<dim3(BATCH * DIN * DSTATE / 256), blk, 0, stream>>>(Asum, Xsum);
    scan_phase3<<<dim3(BATCH * NC * 2), blk, 0, stream>>>(
        u_pre, ub, Bmb, Cmb, zb, Alog, Dp, Xsum, yb);

    // GEMM5 (MFMA): x_mixed = y2 @ Wout^T
    mfma_gemm<EPI_BIAS, false><<<dim3(CDIM / 64, L / 128, BATCH), blk, 0, stream>>>(
        yb, nullptr, Wout, nullptr, x_proj, nullptr, L, CDIM, DIN, 1 << 30, (long)L * DIN);
    ln_kernel<<<dim3(L / 32, BATCH), blk, 0, stream>>>(x_proj, gam, bet, out);
}

// Round 5
// 420.848 us; speedup vs baseline: 3.6230x; 1.0311x over previous
//
#include <hip/hip_runtime.h>
#include <math.h>

#define L 4096
#define CDIM 256
#define DIN 512
#define DSTATE 16
#define DTR 16
#define BATCH 4

using f32x4  = __attribute__((ext_vector_type(4))) float;
using bf16x8 = __attribute__((ext_vector_type(8))) __bf16;

__device__ __forceinline__ float silu_f(float x) { return x / (1.f + __expf(-x)); }
// fast softplus: log1p(exp(x)) ~= __logf(1+__expf(x)); abs err < ~1e-6, exact-ish for x>20
__device__ __forceinline__ float softplus_fast(float x) {
    return (x > 20.f) ? x : __logf(1.f + __expf(x));
}

// split fp32 -> (hi, lo) bf16 planes, packed pairwise into uints.
__device__ __forceinline__ void split_pack2(float x0, float x1, unsigned &h, unsigned &l) {
    unsigned b0 = __float_as_uint(x0), b1 = __float_as_uint(x1);
    h = (b0 >> 16) | (b1 & 0xffff0000u);
    float l0 = x0 - __uint_as_float(b0 & 0xffff0000u);
    float l1 = x1 - __uint_as_float(b1 & 0xffff0000u);
    l = (__float_as_uint(l0) >> 16) | (__float_as_uint(l1) & 0xffff0000u);
}

enum { EPI_BIAS = 0, EPI_SPLITUZ = 1, EPI_D34 = 2 };

// ---------------- split-bf16 MFMA GEMM ----------------
// Out[b,m,n] = sum_k A[b,m,k] * Wt[n,k]  via ah*bh + ah*bl + al*bh
// Block tile: M=128, N=64, K-step 32. 4 waves; wave w: rows [32w,32w+32) x 64 n.
// EPI_D34: n<512 -> softplus(acc+bias) -> O0 (delta); n in [512,544) -> O1/O2 (Bm/Cm),
//          weights Wt=Weff for n<512, WtB=Wx[16:] for n>=512.
template<int EPI, bool A_KMAJOR>
__global__ __launch_bounds__(256)
void mfma_gemm(const float* __restrict__ A0, const float* __restrict__ A1,
               const float* __restrict__ Wt, const float* __restrict__ WtB,
               const float* __restrict__ bias,
               float* __restrict__ O0, float* __restrict__ O1, float* __restrict__ O2,
               int M, int N, int K, int kSplit, long strideAb)
{
    __shared__ __align__(16) unsigned short Ah[4][128][8], Al[4][128][8];
    __shared__ __align__(16) unsigned short Bh[4][64][8],  Bl[4][64][8];
    const int b  = blockIdx.z;
    const int n0 = blockIdx.x * 64;
    const int m0 = blockIdx.y * 128;
    const int tid  = threadIdx.x;
    const int lane = tid & 63;
    const int w    = tid >> 6;
    const int lrow = lane & 15;
    const int loct = lane >> 4;

    f32x4 acc[2][4];
    #pragma unroll
    for (int i = 0; i < 2; ++i)
        #pragma unroll
        for (int j = 0; j < 4; ++j)
            acc[i][j] = (f32x4){0.f, 0.f, 0.f, 0.f};

    for (int kk = 0; kk < K; kk += 32) {
        // ---- stage A (128 x 32) ----
        if (A_KMAJOR) {
            int m = tid & 127, half = tid >> 7;
            float v[16];
            #pragma unroll
            for (int j = 0; j < 16; ++j) {
                int kg = kk + half * 16 + j;
                const float* Ap; int kl;
                if (kg < kSplit) { Ap = A0; kl = kg; } else { Ap = A1; kl = kg - kSplit; }
                v[j] = Ap[(long)b * strideAb + (long)kl * M + m0 + m];
            }
            #pragma unroll
            for (int o = 0; o < 2; ++o) {
                uint4 h, l;
                split_pack2(v[o*8+0], v[o*8+1], h.x, l.x);
                split_pack2(v[o*8+2], v[o*8+3], h.y, l.y);
                split_pack2(v[o*8+4], v[o*8+5], h.z, l.z);
                split_pack2(v[o*8+6], v[o*8+7], h.w, l.w);
                *(uint4*)&Ah[half*2+o][m][0] = h;
                *(uint4*)&Al[half*2+o][m][0] = l;
            }
        } else {
            int oct = tid & 3, mA = tid >> 2;
            #pragma unroll
            for (int p = 0; p < 2; ++p) {
                int m = mA + p * 64;
                const float* g = A0 + (long)b * strideAb + (long)(m0 + m) * K + kk + oct * 8;
                float4 x0 = *(const float4*)g;
                float4 x1 = *(const float4*)(g + 4);
                uint4 h, l;
                split_pack2(x0.x, x0.y, h.x, l.x);
                split_pack2(x0.z, x0.w, h.y, l.y);
                split_pack2(x1.x, x1.y, h.z, l.z);
                split_pack2(x1.z, x1.w, h.w, l.w);
                *(uint4*)&Ah[oct][m][0] = h;
                *(uint4*)&Al[oct][m][0] = l;
            }
        }
        // ---- stage B (64 x 32) ----
        {
            int oct = tid & 3, n = tid >> 2;
            int ng = n0 + n;
            float4 x0 = make_float4(0.f, 0.f, 0.f, 0.f), x1 = x0;
            if (EPI == EPI_D34) {
                const float* g = nullptr;
                if (ng < DIN)           g = Wt  + (long)ng * K + kk + oct * 8;
                else if (ng < DIN + 32) g = WtB + (long)(ng - DIN) * K + kk + oct * 8;
                if (g) { x0 = *(const float4*)g; x1 = *(const float4*)(g + 4); }
            } else {
                const float* g = Wt + (long)ng * K + kk + oct * 8;
                x0 = *(const float4*)g; x1 = *(const float4*)(g + 4);
            }
            uint4 h, l;
            split_pack2(x0.x, x0.y, h.x, l.x);
            split_pack2(x0.z, x0.w, h.y, l.y);
            split_pack2(x1.x, x1.y, h.z, l.z);
            split_pack2(x1.z, x1.w, h.w, l.w);
            *(uint4*)&Bh[oct][n][0] = h;
            *(uint4*)&Bl[oct][n][0] = l;
        }
        __syncthreads();
        // ---- MFMA ----
        bf16x8 ah[2], al2[2], bh[4], bl2[4];
        #pragma unroll
        for (int mt = 0; mt < 2; ++mt) {
            ah[mt]  = *(const bf16x8*)&Ah[loct][w*32 + mt*16 + lrow][0];
            al2[mt] = *(const bf16x8*)&Al[loct][w*32 + mt*16 + lrow][0];
        }
        #pragma unroll
        for (int nt = 0; nt < 4; ++nt) {
            bh[nt]  = *(const bf16x8*)&Bh[loct][nt*16 + lrow][0];
            bl2[nt] = *(const bf16x8*)&Bl[loct][nt*16 + lrow][0];
        }
        #pragma unroll
        for (int mt = 0; mt < 2; ++mt)
            #pragma unroll
            for (int nt = 0; nt < 4; ++nt) {
                acc[mt][nt] = __builtin_amdgcn_mfma_f32_16x16x32_bf16(ah[mt],  bh[nt],  acc[mt][nt], 0, 0, 0);
                acc[mt][nt] = __builtin_amdgcn_mfma_f32_16x16x32_bf16(ah[mt],  bl2[nt], acc[mt][nt], 0, 0, 0);
                acc[mt][nt] = __builtin_amdgcn_mfma_f32_16x16x32_bf16(al2[mt], bh[nt],  acc[mt][nt], 0, 0, 0);
            }
        __syncthreads();
    }
    // ---- epilogue: C/D col=lane&15, row=(lane>>4)*4+reg ----
    #pragma unroll
    for (int mt = 0; mt < 2; ++mt) {
        #pragma unroll
        for (int r = 0; r < 4; ++r) {
            int m = m0 + w * 32 + mt * 16 + loct * 4 + r;
            long rowb = (long)b * M + m;
            #pragma unroll
            for (int nt = 0; nt < 4; ++nt) {
                int n = n0 + nt * 16 + lrow;
                float v = acc[mt][nt][r];
                if (EPI == EPI_BIAS) {
                    if (bias) v += bias[n];
                    O0[rowb * N + n] = v;
                } else if (EPI == EPI_SPLITUZ) {
                    if (n < DIN) O0[rowb * DIN + n] = v;
                    else         O1[rowb * DIN + (n - DIN)] = v;
                } else if (EPI == EPI_D34) {
                    if (n < DIN)            O0[rowb * DIN + n] = softplus_fast(v + bias[n]);
                    else if (n < DIN + 16)  O1[rowb * 16 + (n - DIN)] = v;
                    else if (n < DIN + 32)  O2[rowb * 16 + (n - DIN - 16)] = v;
                }
            }
        }
    }
}

// ---------------- Weff = Wdt (512x16) @ Wx[:16] (16x512) -> (512x512) ----------------
__global__ __launch_bounds__(256)
void weff_kernel(const float* __restrict__ Wdt, const float* __restrict__ Wx,
                 float* __restrict__ Weff)
{
    int idx = blockIdx.x * 256 + threadIdx.x;   // n*512 + k
    int n = idx >> 9, k = idx & 511;
    float acc = 0.f;
    #pragma unroll
    for (int r = 0; r < DTR; ++r)
        acc += Wdt[n * DTR + r] * Wx[r * DIN + k];
    Weff[idx] = acc;
}

// ---------------- depthwise causal conv (k=4) + silu ----------------
__global__ __launch_bounds__(256)
void conv_silu_kernel(const float* __restrict__ u_pre, const float* __restrict__ cw,
                      const float* __restrict__ cb, float* __restrict__ u)
{
    long idx = (long)blockIdx.x * blockDim.x + threadIdx.x;
    int d = (int)(idx % DIN);
    long bl = idx / DIN;
    int l = (int)(bl % L);
    long brow = bl - l;
    float v = cb[d];
    #pragma unroll
    for (int j = 0; j < 4; ++j) {
        int li = l - 3 + j;
        if (li >= 0) v += u_pre[(brow + li) * DIN + d] * cw[d * 4 + j];
    }
    u[idx] = silu_f(v);
}

// ---------------- chunked parallel selective scan, d-per-lane ----------------
#define NC 128
#define LC (L / NC)

__global__ __launch_bounds__(256)
void scan_phase1(const float* __restrict__ delta, const float* __restrict__ u,
                 const float* __restrict__ Bm, const float* __restrict__ A_log,
                 float* __restrict__ Asum, float* __restrict__ Xsum)
{
    __shared__ float sB[LC][DSTATE];
    const int gd = blockIdx.x & 1;
    const int c  = (blockIdx.x >> 1) & (NC - 1);
    const int b  = blockIdx.x >> 8;
    const int d  = gd * 256 + threadIdx.x;
    const int t0 = c * LC;
    float Arow[DSTATE];
    #pragma unroll
    for (int q = 0; q < 4; ++q) {
        float4 v = *(const float4*)&A_log[d * DSTATE + q * 4];
        Arow[q * 4 + 0] = -__expf(v.x);
        Arow[q * 4 + 1] = -__expf(v.y);
        Arow[q * 4 + 2] = -__expf(v.z);
        Arow[q * 4 + 3] = -__expf(v.w);
    }
    for (int i = threadIdx.x; i < LC * DSTATE; i += 256)
        sB[i >> 4][i & 15] = Bm[((long)b * L + t0 + (i >> 4)) * DSTATE + (i & 15)];
    __syncthreads();
    float P[DSTATE], X[DSTATE];
    #pragma unroll
    for (int s = 0; s < DSTATE; ++s) { P[s] = 1.f; X[s] = 0.f; }
    for (int t = 0; t < LC; ++t) {
        long gidx = ((long)b * L + t0 + t) * DIN + d;
        float dlt = delta[gidx];
        float du  = dlt * u[gidx];
        #pragma unroll
        for (int s = 0; s < DSTATE; ++s) {
            float a = __expf(dlt * Arow[s]);
            P[s] *= a;
            X[s] = a * X[s] + du * sB[t][s];
        }
    }
    long o = (((long)b * NC + c) * DIN + d) * DSTATE;
    #pragma unroll
    for (int q = 0; q < 4; ++q) {
        *(float4*)&Asum[o + q * 4] = make_float4(P[q*4], P[q*4+1], P[q*4+2], P[q*4+3]);
        *(float4*)&Xsum[o + q * 4] = make_float4(X[q*4], X[q*4+1], X[q*4+2], X[q*4+3]);
    }
}

__global__ __launch_bounds__(256)
void scan_phase2(const float* __restrict__ Asum, float* __restrict__ Xsum)
{
    int lane = blockIdx.x * 256 + threadIdx.x;
    int b = lane / (DIN * DSTATE);
    int rem = lane % (DIN * DSTATE);
    float h = 0.f;
    for (int c = 0; c < NC; ++c) {
        long idx = ((long)b * NC + c) * (DIN * DSTATE) + rem;
        float A = Asum[idx], X = Xsum[idx];
        Xsum[idx] = h;
        h = A * h + X;
    }
}

__global__ __launch_bounds__(256)
void scan_phase3(const float* __restrict__ delta, const float* __restrict__ u,
                 const float* __restrict__ Bm, const float* __restrict__ Cm,
                 const float* __restrict__ z, const float* __restrict__ A_log,
                 const float* __restrict__ Dp, const float* __restrict__ Hinit,
                 float* __restrict__ y2)
{
    __shared__ float sB[LC][DSTATE], sC[LC][DSTATE];
    const int gd = blockIdx.x & 1;
    const int c  = (blockIdx.x >> 1) & (NC - 1);
    const int b  = blockIdx.x >> 8;
    const int d  = gd * 256 + threadIdx.x;
    const int t0 = c * LC;
    float Arow[DSTATE];
    #pragma unroll
    for (int q = 0; q < 4; ++q) {
        float4 v = *(const float4*)&A_log[d * DSTATE + q * 4];
        Arow[q * 4 + 0] = -__expf(v.x);
        Arow[q * 4 + 1] = -__expf(v.y);
        Arow[q * 4 + 2] = -__expf(v.z);
        Arow[q * 4 + 3] = -__expf(v.w);
    }
    for (int i = threadIdx.x; i < LC * DSTATE; i += 256) {
        long gidx = ((long)b * L + t0 + (i >> 4)) * DSTATE + (i & 15);
        sB[i >> 4][i & 15] = Bm[gidx];
        sC[i >> 4][i & 15] = Cm[gidx];
    }
    float h[DSTATE];
    {
        long o = (((long)b * NC + c) * DIN + d) * DSTATE;
        #pragma unroll
        for (int q = 0; q < 4; ++q) {
            float4 v = *(const float4*)&Hinit[o + q * 4];
            h[q * 4 + 0] = v.x; h[q * 4 + 1] = v.y;
            h[q * 4 + 2] = v.z; h[q * 4 + 3] = v.w;
        }
    }
    const float Dval = Dp[d];
    __syncthreads();
    for (int t = 0; t < LC; ++t) {
        long gidx = ((long)b * L + t0 + t) * DIN + d;
        float dlt = delta[gidx];
        float uu  = u[gidx];
        float zz  = z[gidx];
        float du  = dlt * uu;
        float y = 0.f;
        #pragma unroll
        for (int s = 0; s < DSTATE; ++s) {
            float a = __expf(dlt * Arow[s]);
            h[s] = h[s] * a + du * sB[t][s];
            y += h[s] * sC[t][s];
        }
        y2[gidx] = (y + uu * Dval) * silu_f(zz);
    }
}

// ---------------- LayerNorm over C + transpose to (B,C,L) ----------------
__global__ __launch_bounds__(256)
void ln_kernel(const float* __restrict__ X, const float* __restrict__ gamma,
               const float* __restrict__ beta, float* __restrict__ out)
{
    __shared__ float tile[32][257];
    __shared__ float sMu[32], sRs[32];
    const int l0 = blockIdx.x * 32;
    const int b  = blockIdx.y;
    const int tid = threadIdx.x;
    for (int i = tid; i < 32 * 256; i += 256) {
        int l = i >> 8, c = i & 255;
        tile[l][c] = X[((long)b * L + l0 + l) * CDIM + c];
    }
    __syncthreads();
    {
        int l = tid >> 3, sub = tid & 7;
        float s1 = 0.f, s2 = 0.f;
        for (int c = sub * 32; c < sub * 32 + 32; ++c) {
            float v = tile[l][c];
            s1 += v; s2 += v * v;
        }
        s1 += __shfl_xor(s1, 1); s2 += __shfl_xor(s2, 1);
        s1 += __shfl_xor(s1, 2); s2 += __shfl_xor(s2, 2);
        s1 += __shfl_xor(s1, 4); s2 += __shfl_xor(s2, 4);
        if (sub == 0) {
            float mu = s1 * (1.f / 256.f);
            float var = s2 * (1.f / 256.f) - mu * mu;
            sMu[l] = mu;
            sRs[l] = rsqrtf(var + 1e-5f);
        }
    }
    __syncthreads();
    for (int i = tid; i < 32 * 256; i += 256) {
        int ll = i & 31, c = i >> 5;
        float v = (tile[ll][c] - sMu[ll]) * sRs[ll] * gamma[c] + beta[c];
        out[((long)b * CDIM + c) * L + l0 + ll] = v;
    }
}

extern "C" void kernel_launch(void* const* d_in, const int* in_sizes, int n_in,
                              void* d_out, int out_size, void* d_ws, size_t ws_size,
                              hipStream_t stream)
{
    const float* sp   = (const float*)d_in[0];
    const float* fq   = (const float*)d_in[1];
    const float* Wp   = (const float*)d_in[2];
    const float* bp   = (const float*)d_in[3];
    const float* Win  = (const float*)d_in[4];
    const float* cw   = (const float*)d_in[5];
    const float* cb   = (const float*)d_in[6];
    const float* Wx   = (const float*)d_in[7];
    const float* Wdt  = (const float*)d_in[8];
    const float* bdt  = (const float*)d_in[9];
    const float* Alog = (const float*)d_in[10];
    const float* Dp   = (const float*)d_in[11];
    const float* Wout = (const float*)d_in[12];
    const float* gam  = (const float*)d_in[13];
    const float* bet  = (const float*)d_in[14];
    float* out = (float*)d_out;
    float* ws  = (float*)d_ws;

    size_t off = 0;
    float* x_proj = ws + off; off += (size_t)BATCH * L * CDIM;  // reused: Asum/Xsum, then x_mixed
    float* u_pre  = ws + off; off += (size_t)BATCH * L * DIN;   // reused as delta
    float* zb     = ws + off; off += (size_t)BATCH * L * DIN;
    float* ub     = ws + off; off += (size_t)BATCH * L * DIN;
    float* yb     = ws + off; off += (size_t)BATCH * L * DIN;
    float* weff   = ws + off; off += (size_t)DIN * DIN;         // 512x512 effective dt-weight
    float* Bmb    = ws + off; off += (size_t)BATCH * L * DSTATE;
    float* Cmb    = ws + off; off += (size_t)BATCH * L * DSTATE;

    float* Asum = x_proj;
    float* Xsum = x_proj + (size_t)BATCH * NC * DIN * DSTATE;

    dim3 blk(256);
    // Weff = Wdt @ Wx[:16]  (tiny)
    weff_kernel<<<dim3(DIN * DIN / 256), blk, 0, stream>>>(Wdt, Wx, weff);
    // GEMM1 (MFMA): x_proj = x_cat @ Wp^T + bp   (A K-major, split at k=256)
    mfma_gemm<EPI_BIAS, true><<<dim3(CDIM / 64, L / 128, BATCH), blk, 0, stream>>>(
        sp, fq, Wp, nullptr, bp, x_proj, nullptr, nullptr, L, CDIM, 2 * CDIM, CDIM, (long)CDIM * L);
    // GEMM2 (MFMA): xz = x_proj @ Win^T -> split u_pre / z
    mfma_gemm<EPI_SPLITUZ, false><<<dim3(2 * DIN / 64, L / 128, BATCH), blk, 0, stream>>>(
        x_proj, nullptr, Win, nullptr, nullptr, u_pre, zb, nullptr, L, 2 * DIN, CDIM, 1 << 30, (long)L * CDIM);
    conv_silu_kernel<<<dim3((BATCH * L * DIN) / 256), blk, 0, stream>>>(u_pre, cw, cb, ub);
    // GEMM3+4 fused (MFMA): [delta | Bm | Cm] = u @ [Weff | Wx[16:48]]^T, softplus on delta
    mfma_gemm<EPI_D34, false><<<dim3(9, L / 128, BATCH), blk, 0, stream>>>(
        ub, nullptr, weff, Wx + DTR * DIN, bdt, u_pre, Bmb, Cmb, L, DIN + 32, DIN, 1 << 30, (long)L * DIN);

    scan_phase1<<<dim3(BATCH * NC * 2), blk, 0, stream>>>(u_pre, ub, Bmb, Alog, Asum, Xsum);
    scan_phase2<<<dim3(BATCH * DIN * DSTATE / 256), blk, 0, stream>>>(Asum, Xsum);
    scan_phase3<<<dim3(BATCH * NC * 2), blk, 0, stream>>>(
        u_pre, ub, Bmb, Cmb, zb, Alog, Dp, Xsum, yb);

    // GEMM5 (MFMA): x_mixed = y2 @ Wout^T
    mfma_gemm<EPI_BIAS, false><<<dim3(CDIM / 64, L / 128, BATCH), blk, 0, stream>>>(
        yb, nullptr, Wout, nullptr, nullptr, x_proj, nullptr, nullptr, L, CDIM, DIN, 1 << 30, (long)L * DIN);
    ln_kernel<<<dim3(L / 32, BATCH), blk, 0, stream>>>(x_proj, gam, bet, out);
}

// Round 6
// 397.977 us; speedup vs baseline: 3.8312x; 1.0575x over previous
//
#include <hip/hip_runtime.h>
#include <math.h>

#define L 4096
#define CDIM 256
#define DIN 512
#define DSTATE 16
#define DTR 16
#define BATCH 4

using f32x4  = __attribute__((ext_vector_type(4))) float;
using bf16x8 = __attribute__((ext_vector_type(8))) __bf16;

__device__ __forceinline__ float silu_f(float x) { return x / (1.f + __expf(-x)); }
__device__ __forceinline__ float softplus_fast(float x) {
    return (x > 20.f) ? x : __logf(1.f + __expf(x));
}

// split fp32 -> (hi, lo) bf16 planes, packed pairwise into uints.
__device__ __forceinline__ void split_pack2(float x0, float x1, unsigned &h, unsigned &l) {
    unsigned b0 = __float_as_uint(x0), b1 = __float_as_uint(x1);
    h = (b0 >> 16) | (b1 & 0xffff0000u);
    float l0 = x0 - __uint_as_float(b0 & 0xffff0000u);
    float l1 = x1 - __uint_as_float(b1 & 0xffff0000u);
    l = (__float_as_uint(l0) >> 16) | (__float_as_uint(l1) & 0xffff0000u);
}

enum { EPI_BIAS = 0, EPI_SPLITUZ = 1, EPI_D34 = 2 };

// ---------------- split-bf16 MFMA GEMM (pipelined, XCD-sticky, padded LDS) ----------------
// Out[b,m,n] = sum_k A[b,m,k] * Wt[n,k]  via ah*bh + ah*bl + al*bh
// Block tile M=128, N=64, K-step 32. LDS rows [row][40] (32 used + 8 pad shorts):
// row stride 20 dwords -> staging writes & frag reads spread across banks (<=2-way).
#define LDK 40
template<int EPI, bool A_KMAJOR>
__global__ __launch_bounds__(256)
void mfma_gemm(const float* __restrict__ A0, const float* __restrict__ A1,
               const float* __restrict__ Wt, const float* __restrict__ WtB,
               const float* __restrict__ bias,
               float* __restrict__ O0, float* __restrict__ O1, float* __restrict__ O2,
               int M, int N, int K, int kSplit, long strideAb, int nBlk)
{
    __shared__ __align__(16) unsigned short Ah[128][LDK], Al[128][LDK];
    __shared__ __align__(16) unsigned short Bh[64][LDK],  Bl[64][LDK];
    const int mBlk = M / 128;
    // XCD-sticky swizzle: all n-blocks of one (b,m) A-tile share bid%8 -> same XCD L2
    const int bid = blockIdx.x;
    const int r = bid & 7, q = bid >> 3;
    const int ni = q % nBlk;
    const int mg = (q / nBlk) * 8 + r;            // [0, BATCH*mBlk)
    const int b = mg / mBlk, m_idx = mg - b * mBlk;
    const int n0 = ni * 64, m0 = m_idx * 128;
    const int tid  = threadIdx.x;
    const int lane = tid & 63;
    const int w    = tid >> 6;
    const int lrow = lane & 15;
    const int loct = lane >> 4;

    f32x4 acc[2][4];
    #pragma unroll
    for (int i = 0; i < 2; ++i)
        #pragma unroll
        for (int j = 0; j < 4; ++j)
            acc[i][j] = (f32x4){0.f, 0.f, 0.f, 0.f};

    float va[16];  // A prefetch regs
    float vb[8];   // B prefetch regs

    auto loadA = [&](int kk) {
        if (A_KMAJOR) {
            int m = tid & 127, half = tid >> 7;
            #pragma unroll
            for (int j = 0; j < 16; ++j) {
                int kg = kk + half * 16 + j;
                const float* Ap; int kl;
                if (kg < kSplit) { Ap = A0; kl = kg; } else { Ap = A1; kl = kg - kSplit; }
                va[j] = Ap[(long)b * strideAb + (long)kl * M + m0 + m];
            }
        } else {
            int oct = tid & 3, mA = tid >> 2;
            #pragma unroll
            for (int p = 0; p < 2; ++p) {
                const float* g = A0 + (long)b * strideAb + (long)(m0 + mA + p * 64) * K + kk + oct * 8;
                float4 x0 = *(const float4*)g;
                float4 x1 = *(const float4*)(g + 4);
                va[p*8+0] = x0.x; va[p*8+1] = x0.y; va[p*8+2] = x0.z; va[p*8+3] = x0.w;
                va[p*8+4] = x1.x; va[p*8+5] = x1.y; va[p*8+6] = x1.z; va[p*8+7] = x1.w;
            }
        }
    };
    auto loadB = [&](int kk) {
        int oct = tid & 3, n = tid >> 2;
        int ng = n0 + n;
        float4 x0 = make_float4(0.f, 0.f, 0.f, 0.f), x1 = x0;
        if (EPI == EPI_D34) {
            const float* g = nullptr;
            if (ng < DIN)           g = Wt  + (long)ng * K + kk + oct * 8;
            else if (ng < DIN + 32) g = WtB + (long)(ng - DIN) * K + kk + oct * 8;
            if (g) { x0 = *(const float4*)g; x1 = *(const float4*)(g + 4); }
        } else {
            const float* g = Wt + (long)ng * K + kk + oct * 8;
            x0 = *(const float4*)g; x1 = *(const float4*)(g + 4);
        }
        vb[0] = x0.x; vb[1] = x0.y; vb[2] = x0.z; vb[3] = x0.w;
        vb[4] = x1.x; vb[5] = x1.y; vb[6] = x1.z; vb[7] = x1.w;
    };
    auto storeAB = [&]() {
        if (A_KMAJOR) {
            int m = tid & 127, half = tid >> 7;
            #pragma unroll
            for (int o = 0; o < 2; ++o) {
                uint4 h, l;
                split_pack2(va[o*8+0], va[o*8+1], h.x, l.x);
                split_pack2(va[o*8+2], va[o*8+3], h.y, l.y);
                split_pack2(va[o*8+4], va[o*8+5], h.z, l.z);
                split_pack2(va[o*8+6], va[o*8+7], h.w, l.w);
                *(uint4*)&Ah[m][half*16 + o*8] = h;
                *(uint4*)&Al[m][half*16 + o*8] = l;
            }
        } else {
            int oct = tid & 3, mA = tid >> 2;
            #pragma unroll
            for (int p = 0; p < 2; ++p) {
                uint4 h, l;
                split_pack2(va[p*8+0], va[p*8+1], h.x, l.x);
                split_pack2(va[p*8+2], va[p*8+3], h.y, l.y);
                split_pack2(va[p*8+4], va[p*8+5], h.z, l.z);
                split_pack2(va[p*8+6], va[p*8+7], h.w, l.w);
                *(uint4*)&Ah[mA + p*64][oct*8] = h;
                *(uint4*)&Al[mA + p*64][oct*8] = l;
            }
        }
        {
            int oct = tid & 3, n = tid >> 2;
            uint4 h, l;
            split_pack2(vb[0], vb[1], h.x, l.x);
            split_pack2(vb[2], vb[3], h.y, l.y);
            split_pack2(vb[4], vb[5], h.z, l.z);
            split_pack2(vb[6], vb[7], h.w, l.w);
            *(uint4*)&Bh[n][oct*8] = h;
            *(uint4*)&Bl[n][oct*8] = l;
        }
    };

    loadA(0); loadB(0);
    for (int kk = 0; kk < K; kk += 32) {
        storeAB();
        __syncthreads();
        if (kk + 32 < K) { loadA(kk + 32); loadB(kk + 32); }  // in flight during MFMA
        bf16x8 ah[2], al2[2], bh[4], bl2[4];
        #pragma unroll
        for (int mt = 0; mt < 2; ++mt) {
            ah[mt]  = *(const bf16x8*)&Ah[w*32 + mt*16 + lrow][loct*8];
            al2[mt] = *(const bf16x8*)&Al[w*32 + mt*16 + lrow][loct*8];
        }
        #pragma unroll
        for (int nt = 0; nt < 4; ++nt) {
            bh[nt]  = *(const bf16x8*)&Bh[nt*16 + lrow][loct*8];
            bl2[nt] = *(const bf16x8*)&Bl[nt*16 + lrow][loct*8];
        }
        #pragma unroll
        for (int mt = 0; mt < 2; ++mt)
            #pragma unroll
            for (int nt = 0; nt < 4; ++nt) {
                acc[mt][nt] = __builtin_amdgcn_mfma_f32_16x16x32_bf16(ah[mt],  bh[nt],  acc[mt][nt], 0, 0, 0);
                acc[mt][nt] = __builtin_amdgcn_mfma_f32_16x16x32_bf16(ah[mt],  bl2[nt], acc[mt][nt], 0, 0, 0);
                acc[mt][nt] = __builtin_amdgcn_mfma_f32_16x16x32_bf16(al2[mt], bh[nt],  acc[mt][nt], 0, 0, 0);
            }
        __syncthreads();
    }
    // ---- epilogue: C/D col=lane&15, row=(lane>>4)*4+reg ----
    #pragma unroll
    for (int mt = 0; mt < 2; ++mt) {
        #pragma unroll
        for (int r4 = 0; r4 < 4; ++r4) {
            int m = m0 + w * 32 + mt * 16 + loct * 4 + r4;
            long rowb = (long)b * M + m;
            #pragma unroll
            for (int nt = 0; nt < 4; ++nt) {
                int n = n0 + nt * 16 + lrow;
                float v = acc[mt][nt][r4];
                if (EPI == EPI_BIAS) {
                    if (bias) v += bias[n];
                    O0[rowb * N + n] = v;
                } else if (EPI == EPI_SPLITUZ) {
                    if (n < DIN) O0[rowb * DIN + n] = v;
                    else         O1[rowb * DIN + (n - DIN)] = v;
                } else if (EPI == EPI_D34) {
                    if (n < DIN)            O0[rowb * DIN + n] = softplus_fast(v + bias[n]);
                    else if (n < DIN + 16)  O1[rowb * 16 + (n - DIN)] = v;
                    else if (n < DIN + 32)  O2[rowb * 16 + (n - DIN - 16)] = v;
                }
            }
        }
    }
}

// ---------------- Weff = Wdt (512x16) @ Wx[:16] (16x512) -> (512x512) ----------------
__global__ __launch_bounds__(256)
void weff_kernel(const float* __restrict__ Wdt, const float* __restrict__ Wx,
                 float* __restrict__ Weff)
{
    int idx = blockIdx.x * 256 + threadIdx.x;   // n*512 + k
    int n = idx >> 9, k = idx & 511;
    float acc = 0.f;
    #pragma unroll
    for (int r = 0; r < DTR; ++r)
        acc += Wdt[n * DTR + r] * Wx[r * DIN + k];
    Weff[idx] = acc;
}

// ---------------- depthwise causal conv (k=4) + silu ----------------
__global__ __launch_bounds__(256)
void conv_silu_kernel(const float* __restrict__ u_pre, const float* __restrict__ cw,
                      const float* __restrict__ cb, float* __restrict__ u)
{
    long idx = (long)blockIdx.x * blockDim.x + threadIdx.x;
    int d = (int)(idx % DIN);
    long bl = idx / DIN;
    int l = (int)(bl % L);
    long brow = bl - l;
    float v = cb[d];
    #pragma unroll
    for (int j = 0; j < 4; ++j) {
        int li = l - 3 + j;
        if (li >= 0) v += u_pre[(brow + li) * DIN + d] * cw[d * 4 + j];
    }
    u[idx] = silu_f(v);
}

// ---------------- chunked parallel selective scan, d-per-lane ----------------
#define NC 128
#define LC (L / NC)

__global__ __launch_bounds__(256)
void scan_phase1(const float* __restrict__ delta, const float* __restrict__ u,
                 const float* __restrict__ Bm, const float* __restrict__ A_log,
                 float* __restrict__ Asum, float* __restrict__ Xsum)
{
    __shared__ float sB[LC][DSTATE];
    const int gd = blockIdx.x & 1;
    const int c  = (blockIdx.x >> 1) & (NC - 1);
    const int b  = blockIdx.x >> 8;
    const int d  = gd * 256 + threadIdx.x;
    const int t0 = c * LC;
    float Arow[DSTATE];
    #pragma unroll
    for (int q = 0; q < 4; ++q) {
        float4 v = *(const float4*)&A_log[d * DSTATE + q * 4];
        Arow[q * 4 + 0] = -__expf(v.x);
        Arow[q * 4 + 1] = -__expf(v.y);
        Arow[q * 4 + 2] = -__expf(v.z);
        Arow[q * 4 + 3] = -__expf(v.w);
    }
    for (int i = threadIdx.x; i < LC * DSTATE; i += 256)
        sB[i >> 4][i & 15] = Bm[((long)b * L + t0 + (i >> 4)) * DSTATE + (i & 15)];
    __syncthreads();
    float P[DSTATE], X[DSTATE];
    #pragma unroll
    for (int s = 0; s < DSTATE; ++s) { P[s] = 1.f; X[s] = 0.f; }
    for (int t = 0; t < LC; ++t) {
        long gidx = ((long)b * L + t0 + t) * DIN + d;
        float dlt = delta[gidx];
        float du  = dlt * u[gidx];
        #pragma unroll
        for (int s = 0; s < DSTATE; ++s) {
            float a = __expf(dlt * Arow[s]);
            P[s] *= a;
            X[s] = a * X[s] + du * sB[t][s];
        }
    }
    long o = (((long)b * NC + c) * DIN + d) * DSTATE;
    #pragma unroll
    for (int q = 0; q < 4; ++q) {
        *(float4*)&Asum[o + q * 4] = make_float4(P[q*4], P[q*4+1], P[q*4+2], P[q*4+3]);
        *(float4*)&Xsum[o + q * 4] = make_float4(X[q*4], X[q*4+1], X[q*4+2], X[q*4+3]);
    }
}

__global__ __launch_bounds__(256)
void scan_phase2(const float* __restrict__ Asum, float* __restrict__ Xsum)
{
    int lane = blockIdx.x * 256 + threadIdx.x;
    int b = lane / (DIN * DSTATE);
    int rem = lane % (DIN * DSTATE);
    float h = 0.f;
    for (int c = 0; c < NC; ++c) {
        long idx = ((long)b * NC + c) * (DIN * DSTATE) + rem;
        float A = Asum[idx], X = Xsum[idx];
        Xsum[idx] = h;
        h = A * h + X;
    }
}

__global__ __launch_bounds__(256)
void scan_phase3(const float* __restrict__ delta, const float* __restrict__ u,
                 const float* __restrict__ Bm, const float* __restrict__ Cm,
                 const float* __restrict__ z, const float* __restrict__ A_log,
                 const float* __restrict__ Dp, const float* __restrict__ Hinit,
                 float* __restrict__ y2)
{
    __shared__ float sB[LC][DSTATE], sC[LC][DSTATE];
    const int gd = blockIdx.x & 1;
    const int c  = (blockIdx.x >> 1) & (NC - 1);
    const int b  = blockIdx.x >> 8;
    const int d  = gd * 256 + threadIdx.x;
    const int t0 = c * LC;
    float Arow[DSTATE];
    #pragma unroll
    for (int q = 0; q < 4; ++q) {
        float4 v = *(const float4*)&A_log[d * DSTATE + q * 4];
        Arow[q * 4 + 0] = -__expf(v.x);
        Arow[q * 4 + 1] = -__expf(v.y);
        Arow[q * 4 + 2] = -__expf(v.z);
        Arow[q * 4 + 3] = -__expf(v.w);
    }
    for (int i = threadIdx.x; i < LC * DSTATE; i += 256) {
        long gidx = ((long)b * L + t0 + (i >> 4)) * DSTATE + (i & 15);
        sB[i >> 4][i & 15] = Bm[gidx];
        sC[i >> 4][i & 15] = Cm[gidx];
    }
    float h[DSTATE];
    {
        long o = (((long)b * NC + c) * DIN + d) * DSTATE;
        #pragma unroll
        for (int q = 0; q < 4; ++q) {
            float4 v = *(const float4*)&Hinit[o + q * 4];
            h[q * 4 + 0] = v.x; h[q * 4 + 1] = v.y;
            h[q * 4 + 2] = v.z; h[q * 4 + 3] = v.w;
        }
    }
    const float Dval = Dp[d];
    __syncthreads();
    for (int t = 0; t < LC; ++t) {
        long gidx = ((long)b * L + t0 + t) * DIN + d;
        float dlt = delta[gidx];
        float uu  = u[gidx];
        float zz  = z[gidx];
        float du  = dlt * uu;
        float y = 0.f;
        #pragma unroll
        for (int s = 0; s < DSTATE; ++s) {
            float a = __expf(dlt * Arow[s]);
            h[s] = h[s] * a + du * sB[t][s];
            y += h[s] * sC[t][s];
        }
        y2[gidx] = (y + uu * Dval) * silu_f(zz);
    }
}

// ---------------- LayerNorm over C + transpose to (B,C,L) ----------------
__global__ __launch_bounds__(256)
void ln_kernel(const float* __restrict__ X, const float* __restrict__ gamma,
               const float* __restrict__ beta, float* __restrict__ out)
{
    __shared__ float tile[32][257];
    __shared__ float sMu[32], sRs[32];
    const int l0 = blockIdx.x * 32;
    const int b  = blockIdx.y;
    const int tid = threadIdx.x;
    for (int i = tid; i < 32 * 256; i += 256) {
        int l = i >> 8, c = i & 255;
        tile[l][c] = X[((long)b * L + l0 + l) * CDIM + c];
    }
    __syncthreads();
    {
        int l = tid >> 3, sub = tid & 7;
        float s1 = 0.f, s2 = 0.f;
        for (int c = sub * 32; c < sub * 32 + 32; ++c) {
            float v = tile[l][c];
            s1 += v; s2 += v * v;
        }
        s1 += __shfl_xor(s1, 1); s2 += __shfl_xor(s2, 1);
        s1 += __shfl_xor(s1, 2); s2 += __shfl_xor(s2, 2);
        s1 += __shfl_xor(s1, 4); s2 += __shfl_xor(s2, 4);
        if (sub == 0) {
            float mu = s1 * (1.f / 256.f);
            float var = s2 * (1.f / 256.f) - mu * mu;
            sMu[l] = mu;
            sRs[l] = rsqrtf(var + 1e-5f);
        }
    }
    __syncthreads();
    for (int i = tid; i < 32 * 256; i += 256) {
        int ll = i & 31, c = i >> 5;
        float v = (tile[ll][c] - sMu[ll]) * sRs[ll] * gamma[c] + beta[c];
        out[((long)b * CDIM + c) * L + l0 + ll] = v;
    }
}

extern "C" void kernel_launch(void* const* d_in, const int* in_sizes, int n_in,
                              void* d_out, int out_size, void* d_ws, size_t ws_size,
                              hipStream_t stream)
{
    const float* sp   = (const float*)d_in[0];
    const float* fq   = (const float*)d_in[1];
    const float* Wp   = (const float*)d_in[2];
    const float* bp   = (const float*)d_in[3];
    const float* Win  = (const float*)d_in[4];
    const float* cw   = (const float*)d_in[5];
    const float* cb   = (const float*)d_in[6];
    const float* Wx   = (const float*)d_in[7];
    const float* Wdt  = (const float*)d_in[8];
    const float* bdt  = (const float*)d_in[9];
    const float* Alog = (const float*)d_in[10];
    const float* Dp   = (const float*)d_in[11];
    const float* Wout = (const float*)d_in[12];
    const float* gam  = (const float*)d_in[13];
    const float* bet  = (const float*)d_in[14];
    float* out = (float*)d_out;
    float* ws  = (float*)d_ws;

    size_t off = 0;
    float* x_proj = ws + off; off += (size_t)BATCH * L * CDIM;  // reused: Asum/Xsum, then x_mixed
    float* u_pre  = ws + off; off += (size_t)BATCH * L * DIN;   // reused as delta
    float* zb     = ws + off; off += (size_t)BATCH * L * DIN;
    float* ub     = ws + off; off += (size_t)BATCH * L * DIN;
    float* yb     = ws + off; off += (size_t)BATCH * L * DIN;
    float* weff   = ws + off; off += (size_t)DIN * DIN;
    float* Bmb    = ws + off; off += (size_t)BATCH * L * DSTATE;
    float* Cmb    = ws + off; off += (size_t)BATCH * L * DSTATE;

    float* Asum = x_proj;
    float* Xsum = x_proj + (size_t)BATCH * NC * DIN * DSTATE;

    dim3 blk(256);
    weff_kernel<<<dim3(DIN * DIN / 256), blk, 0, stream>>>(Wdt, Wx, weff);
    // GEMM1 (MFMA): x_proj = x_cat @ Wp^T + bp   (A K-major, split at k=256); nBlk=4
    mfma_gemm<EPI_BIAS, true><<<dim3(BATCH * (L/128) * (CDIM/64)), blk, 0, stream>>>(
        sp, fq, Wp, nullptr, bp, x_proj, nullptr, nullptr,
        L, CDIM, 2 * CDIM, CDIM, (long)CDIM * L, CDIM/64);
    // GEMM2 (MFMA): xz = x_proj @ Win^T -> split u_pre / z; nBlk=16
    mfma_gemm<EPI_SPLITUZ, false><<<dim3(BATCH * (L/128) * (2*DIN/64)), blk, 0, stream>>>(
        x_proj, nullptr, Win, nullptr, nullptr, u_pre, zb, nullptr,
        L, 2 * DIN, CDIM, 1 << 30, (long)L * CDIM, 2*DIN/64);
    conv_silu_kernel<<<dim3((BATCH * L * DIN) / 256), blk, 0, stream>>>(u_pre, cw, cb, ub);
    // GEMM3+4 fused (MFMA): [delta | Bm | Cm] = u @ [Weff | Wx[16:48]]^T; nBlk=9
    mfma_gemm<EPI_D34, false><<<dim3(BATCH * (L/128) * 9), blk, 0, stream>>>(
        ub, nullptr, weff, Wx + DTR * DIN, bdt, u_pre, Bmb, Cmb,
        L, DIN + 32, DIN, 1 << 30, (long)L * DIN, 9);

    scan_phase1<<<dim3(BATCH * NC * 2), blk, 0, stream>>>(u_pre, ub, Bmb, Alog, Asum, Xsum);
    scan_phase2<<<dim3(BATCH * DIN * DSTATE / 256), blk, 0, stream>>>(Asum, Xsum);
    scan_phase3<<<dim3(BATCH * NC * 2), blk, 0, stream>>>(
        u_pre, ub, Bmb, Cmb, zb, Alog, Dp, Xsum, yb);

    // GEMM5 (MFMA): x_mixed = y2 @ Wout^T; nBlk=4
    mfma_gemm<EPI_BIAS, false><<<dim3(BATCH * (L/128) * (CDIM/64)), blk, 0, stream>>>(
        yb, nullptr, Wout, nullptr, nullptr, x_proj, nullptr, nullptr,
        L, CDIM, DIN, 1 << 30, (long)L * DIN, CDIM/64);
    ln_kernel<<<dim3(L / 32, BATCH), blk, 0, stream>>>(x_proj, gam, bet, out);
}